// Round 8
// baseline (529.651 us; speedup 1.0000x reference)
//
#include <hip/hip_runtime.h>

#define N_NODES 4096
#define CIN     128
#define COUT    256
#define WIDTH   64
#define KDIM    16
#define SLOPE   0.1f
#define WSLOPE  0.2f
#define BN_EPS  1e-5f

typedef float float4u __attribute__((ext_vector_type(4), aligned(4)));

__device__ __forceinline__ float lrelu(float x, float s) { return x > 0.f ? x : s * x; }

// accum layout (256 floats): [midS 64 | midQ 64 | outS 64 | outQ 64]

// ======================= prep: stats_x + rowptr + edge_w =====================
struct EdgeP {
  const int* src; const int* dst;
  const float* Ws; const float* bs;
  float* wbuf; int E; float inv_r; int hl;
};

#define WS_LD 113
#define BS_LD 17
#define NB_STATSX 32
#define NB_ROWPTR 49

__global__ __launch_bounds__(256) void prep_kernel(
    const float* __restrict__ x,
    const float* __restrict__ id_g, const float* __restrict__ id_b,
    const float* __restrict__ in_g, const float* __restrict__ in_b,
    float* __restrict__ sA, float* __restrict__ hA,
    float* __restrict__ sB, float* __restrict__ hB,
    int* __restrict__ rowp, float* __restrict__ accum,
    EdgeP e0, EdgeP e1, EdgeP e2,
    const float* __restrict__ pos, const float* __restrict__ ori,
    const int* __restrict__ seq,
    int nb1, int nb2)
{
  int bx = blockIdx.x, t = threadIdx.x;

  if (bx < NB_STATSX) {
    if (bx == 0) accum[t] = 0.f;          // zero BN accumulators (256 floats)
    // ---- column stats of x (4 channels per block) + both affines ----
    int cg = bx;
    int lane = t & 63, wv = t >> 6;
    float s[4] = {0.f, 0.f, 0.f, 0.f}, q[4] = {0.f, 0.f, 0.f, 0.f};
    for (int r = t; r < N_NODES; r += 256) {
      float4u a = *(const float4u*)(x + (size_t)r * CIN + cg * 4);
      float v[4] = {a.x, a.y, a.z, a.w};
#pragma unroll
      for (int i = 0; i < 4; i++) { s[i] += v[i]; q[i] += v[i] * v[i]; }
    }
#pragma unroll
    for (int m = 1; m < 64; m <<= 1) {
#pragma unroll
      for (int i = 0; i < 4; i++) { s[i] += __shfl_xor(s[i], m, 64); q[i] += __shfl_xor(q[i], m, 64); }
    }
    __shared__ float rs[4][4], rq[4][4];
    if (lane == 0) {
#pragma unroll
      for (int i = 0; i < 4; i++) { rs[wv][i] = s[i]; rq[wv][i] = q[i]; }
    }
    __syncthreads();
    if (t < 4) {
      float S = rs[0][t] + rs[1][t] + rs[2][t] + rs[3][t];
      float Q = rq[0][t] + rq[1][t] + rq[2][t] + rq[3][t];
      float m = S / N_NODES;
      float v = Q / N_NODES - m * m;
      float rsv = rsqrtf(v + BN_EPS);
      int c = cg * 4 + t;
      float sa = id_g[c] * rsv;
      float sb = in_g[c] * rsv;
      sA[c] = sa; hA[c] = id_b[c] - m * sa;
      sB[c] = sb; hB[c] = in_b[c] - m * sb;
    }
    return;
  }

  if (bx < NB_STATSX + NB_ROWPTR) {
    int idx = (bx - NB_STATSX) * 256 + t;
    if (idx >= 3 * (N_NODES + 1)) return;
    int b = idx / (N_NODES + 1);
    int n = idx % (N_NODES + 1);
    const int* d = (b == 0) ? e0.dst : (b == 1) ? e1.dst : e2.dst;
    int E = (b == 0) ? e0.E : (b == 1) ? e1.E : e2.E;
    int lo = 0, hi = E;
    if (n >= N_NODES) lo = E;
    else {
      while (lo < hi) { int mid = (lo + hi) >> 1; if (d[mid] < n) lo = mid + 1; else hi = mid; }
    }
    rowp[(size_t)b * (N_NODES + 1) + n] = lo;
    return;
  }

  // ---- per-edge gate weights ----
  int eb = bx - (NB_STATSX + NB_ROWPTR);
  EdgeP p;
  int base;
  if (eb < nb1)            { p = e0; base = eb; }
  else if (eb < nb1 + nb2) { p = e1; base = eb - nb1; }
  else                     { p = e2; base = eb - nb1 - nb2; }

  __shared__ float wsl[11 * WS_LD];
  __shared__ float bsl[11 * BS_LD];
  int L = 2 * p.hl + 1;
  for (int i = t; i < L * 112; i += 256) {
    int bin = i / 112, r = i - bin * 112;
    wsl[bin * WS_LD + r] = p.Ws[(size_t)bin * 112 + r];
  }
  for (int i = t; i < L * 16; i += 256) {
    int bin = i >> 4, r = i & 15;
    bsl[bin * BS_LD + r] = p.bs[(size_t)bin * 16 + r];
  }
  __syncthreads();

  int e = base * 256 + t;
  if (e >= p.E) return;
  int j = p.src[e], i = p.dst[e];
  float px = pos[j * 3 + 0] - pos[i * 3 + 0];
  float py = pos[j * 3 + 1] - pos[i * 3 + 1];
  float pz = pos[j * 3 + 2] - pos[i * 3 + 2];
  float fi[9], fj[9];
  {
    float4u a0 = *(const float4u*)(ori + (size_t)i * 9);
    float4u a1 = *(const float4u*)(ori + (size_t)i * 9 + 4);
    fi[0] = a0.x; fi[1] = a0.y; fi[2] = a0.z; fi[3] = a0.w;
    fi[4] = a1.x; fi[5] = a1.y; fi[6] = a1.z; fi[7] = a1.w;
    fi[8] = ori[(size_t)i * 9 + 8];
    float4u b0 = *(const float4u*)(ori + (size_t)j * 9);
    float4u b1 = *(const float4u*)(ori + (size_t)j * 9 + 4);
    fj[0] = b0.x; fj[1] = b0.y; fj[2] = b0.z; fj[3] = b0.w;
    fj[4] = b1.x; fj[5] = b1.y; fj[6] = b1.z; fj[7] = b1.w;
    fj[8] = ori[(size_t)j * 9 + 8];
  }
  float dist = sqrtf(px * px + py * py + pz * pz);
  float inv = 1.0f / (dist + 1e-9f);
  float dx = px * inv, dy = py * inv, dz = pz * inv;
  float feat[7];
  feat[0] = dist * p.inv_r;
  feat[1] = fi[0] * dx + fi[1] * dy + fi[2] * dz;
  feat[2] = fi[3] * dx + fi[4] * dy + fi[5] * dz;
  feat[3] = fi[6] * dx + fi[7] * dy + fi[8] * dz;
  feat[4] = fi[0] * fj[0] + fi[1] * fj[1] + fi[2] * fj[2];
  feat[5] = fi[3] * fj[3] + fi[4] * fj[4] + fi[5] * fj[5];
  feat[6] = fi[6] * fj[6] + fi[7] * fj[7] + fi[8] * fj[8];
  int d = seq[j] - seq[i];
  d = d < -p.hl ? -p.hl : (d > p.hl ? p.hl : d);
  int bin = d + p.hl;
  const float* Wp = wsl + bin * WS_LD;
  const float* bp = bsl + bin * BS_LD;
  float w16[KDIM];
#pragma unroll
  for (int k = 0; k < KDIM; k++) {
    float a = bp[k];
#pragma unroll
    for (int c = 0; c < 7; c++) a += feat[c] * Wp[c * KDIM + k];
    w16[k] = lrelu(a, WSLOPE);
  }
  float4* wb = (float4*)(p.wbuf + (size_t)e * KDIM);
#pragma unroll
  for (int k = 0; k < 4; k++)
    wb[k] = make_float4(w16[4 * k], w16[4 * k + 1], w16[4 * k + 2], w16[4 * k + 3]);
}

// =========== gemm2: ident = act_id(x)@id_W | hpre = act_in(x)@in_W ==========
// blocks [0,512): cout path. blocks [512,1024): w64 path (+ mid-BN partial sums)
__global__ __launch_bounds__(256) void gemm2_kernel(
    const float* __restrict__ x,
    const float* __restrict__ sA, const float* __restrict__ hA,
    const float* __restrict__ sB, const float* __restrict__ hB,
    const float* __restrict__ idW, const float* __restrict__ inW,
    float* __restrict__ ident, float* __restrict__ hpre,
    float* __restrict__ accum)
{
  int bx = blockIdx.x, t = threadIdx.x;
  __shared__ float at[8 * CIN];   // 4 KB, bn+lrelu applied
  bool coutp = bx < 512;
  int n0 = (coutp ? bx : bx - 512) * 8;
  {
    int r = t >> 5, c4 = (t & 31) * 4;
    const float* S = coutp ? sA : sB;
    const float* H = coutp ? hA : hB;
    float4u xv = *(const float4u*)(x + (size_t)(n0 + r) * CIN + c4);
    float4u sv = *(const float4u*)(S + c4);
    float4u hv = *(const float4u*)(H + c4);
    float4u o;
    o.x = lrelu(xv.x * sv.x + hv.x, SLOPE);
    o.y = lrelu(xv.y * sv.y + hv.y, SLOPE);
    o.z = lrelu(xv.z * sv.z + hv.z, SLOPE);
    o.w = lrelu(xv.w * sv.w + hv.w, SLOPE);
    *(float4u*)(at + r * CIN + c4) = o;
  }
  __syncthreads();
  if (coutp) {
    float acc[8] = {0.f, 0.f, 0.f, 0.f, 0.f, 0.f, 0.f, 0.f};
    for (int k = 0; k < CIN; k += 4) {
      float w0 = idW[(size_t)(k + 0) * COUT + t];
      float w1 = idW[(size_t)(k + 1) * COUT + t];
      float w2 = idW[(size_t)(k + 2) * COUT + t];
      float w3 = idW[(size_t)(k + 3) * COUT + t];
#pragma unroll
      for (int r8 = 0; r8 < 8; r8++) {
        float4u a = *(const float4u*)(at + r8 * CIN + k);
        acc[r8] += a.x * w0 + a.y * w1 + a.z * w2 + a.w * w3;
      }
    }
#pragma unroll
    for (int r8 = 0; r8 < 8; r8++) ident[(size_t)(n0 + r8) * COUT + t] = acc[r8];
  } else {
    int j = t & 63, g = t >> 6;
    float a0 = 0.f, a1 = 0.f;
    for (int k = 0; k < CIN; k += 4) {
      float w0 = inW[(size_t)(k + 0) * WIDTH + j];
      float w1 = inW[(size_t)(k + 1) * WIDTH + j];
      float w2 = inW[(size_t)(k + 2) * WIDTH + j];
      float w3 = inW[(size_t)(k + 3) * WIDTH + j];
      float4u u = *(const float4u*)(at + (2 * g) * CIN + k);
      float4u v = *(const float4u*)(at + (2 * g + 1) * CIN + k);
      a0 += u.x * w0 + u.y * w1 + u.z * w2 + u.w * w3;
      a1 += v.x * w0 + v.y * w1 + v.z * w2 + v.w * w3;
    }
    hpre[(size_t)(n0 + 2 * g) * WIDTH + j] = a0;
    hpre[(size_t)(n0 + 2 * g + 1) * WIDTH + j] = a1;
    // ---- mid-BN partial sums: block-reduce then 64 global atomics ----
    __shared__ float ps[4][WIDTH], pq[4][WIDTH];
    ps[g][j] = a0 + a1;
    pq[g][j] = a0 * a0 + a1 * a1;
    __syncthreads();
    if (t < WIDTH) {
      atomicAdd(&accum[t],      ps[0][t] + ps[1][t] + ps[2][t] + ps[3][t]);   // midS
      atomicAdd(&accum[64 + t], pq[0][t] + pq[1][t] + pq[2][t] + pq[3][t]);   // midQ
    }
  }
}

// ============== agg3: aggregation + branch GEMM, 4 nodes/block ==============
// Wave wv owns node n0+wv end-to-end (stride-1 edge loop, unroll x4).
// Epilogue: each Wf element loaded once per block, reused for all 4 nodes.
struct AggP {
  const int* src; const float* wbuf; const float* Wf;
  int O; int coloff;
};

#define ALD 68                       // padded k-row stride
#define STRIP (KDIM * ALD + 4)       // 1092 floats; %32 = 4 -> bank shift/strip

__global__ __launch_bounds__(256) void agg3_kernel(
    AggP p0, AggP p1, AggP p2, const int* __restrict__ rowp,
    const float* __restrict__ hpre,
    const float* __restrict__ mid_g, const float* __restrict__ mid_b,
    float* __restrict__ accum, float* __restrict__ cat)
{
  int b = blockIdx.y;
  AggP p = (b == 0) ? p0 : (b == 1) ? p1 : p2;
  int n0 = blockIdx.x * 4, t = threadIdx.x, lane = t & 63, wv = t >> 6;

  __shared__ float lds[4 * STRIP];      // ~17.5 KB
  __shared__ float pw[4][4][32];        // wv, node, col (2 KB)
  __shared__ float sHl[WIDTH], hHl[WIDTH];
  if (t < WIDTH) {
    float m = accum[t] * (1.f / N_NODES);
    float v = accum[64 + t] * (1.f / N_NODES) - m * m;
    float s = mid_g[t] * rsqrtf(v + BN_EPS);
    sHl[t] = s; hHl[t] = mid_b[t] - m * s;
  }
  __syncthreads();
  float scH = sHl[lane], shH = hHl[lane];

  const int* rp = rowp + (size_t)b * (N_NODES + 1);
  int n = n0 + wv;
  int start = rp[n], end = rp[n + 1];

  float acc[KDIM];
#pragma unroll
  for (int k = 0; k < KDIM; k++) acc[k] = 0.f;

  int e = start;
  for (; e + 3 < end; e += 4) {
    int j0 = __builtin_amdgcn_readfirstlane(p.src[e]);
    int j1 = __builtin_amdgcn_readfirstlane(p.src[e + 1]);
    int j2 = __builtin_amdgcn_readfirstlane(p.src[e + 2]);
    int j3 = __builtin_amdgcn_readfirstlane(p.src[e + 3]);
    float r0 = hpre[(size_t)j0 * WIDTH + lane];
    float r1 = hpre[(size_t)j1 * WIDTH + lane];
    float r2 = hpre[(size_t)j2 * WIDTH + lane];
    float r3 = hpre[(size_t)j3 * WIDTH + lane];
    const float4* a0 = (const float4*)(p.wbuf + (size_t)e * KDIM);
    float4 w00 = a0[0], w01 = a0[1], w02 = a0[2],  w03 = a0[3];
    float4 w10 = a0[4], w11 = a0[5], w12 = a0[6],  w13 = a0[7];
    float4 w20 = a0[8], w21 = a0[9], w22 = a0[10], w23 = a0[11];
    float4 w30 = a0[12], w31 = a0[13], w32 = a0[14], w33 = a0[15];
    float hj0 = lrelu(r0 * scH + shH, SLOPE);
    float hj1 = lrelu(r1 * scH + shH, SLOPE);
    float hj2 = lrelu(r2 * scH + shH, SLOPE);
    float hj3 = lrelu(r3 * scH + shH, SLOPE);
    acc[0] += w00.x * hj0; acc[1] += w00.y * hj0; acc[2] += w00.z * hj0; acc[3] += w00.w * hj0;
    acc[4] += w01.x * hj0; acc[5] += w01.y * hj0; acc[6] += w01.z * hj0; acc[7] += w01.w * hj0;
    acc[8] += w02.x * hj0; acc[9] += w02.y * hj0; acc[10] += w02.z * hj0; acc[11] += w02.w * hj0;
    acc[12] += w03.x * hj0; acc[13] += w03.y * hj0; acc[14] += w03.z * hj0; acc[15] += w03.w * hj0;
    acc[0] += w10.x * hj1; acc[1] += w10.y * hj1; acc[2] += w10.z * hj1; acc[3] += w10.w * hj1;
    acc[4] += w11.x * hj1; acc[5] += w11.y * hj1; acc[6] += w11.z * hj1; acc[7] += w11.w * hj1;
    acc[8] += w12.x * hj1; acc[9] += w12.y * hj1; acc[10] += w12.z * hj1; acc[11] += w12.w * hj1;
    acc[12] += w13.x * hj1; acc[13] += w13.y * hj1; acc[14] += w13.z * hj1; acc[15] += w13.w * hj1;
    acc[0] += w20.x * hj2; acc[1] += w20.y * hj2; acc[2] += w20.z * hj2; acc[3] += w20.w * hj2;
    acc[4] += w21.x * hj2; acc[5] += w21.y * hj2; acc[6] += w21.z * hj2; acc[7] += w21.w * hj2;
    acc[8] += w22.x * hj2; acc[9] += w22.y * hj2; acc[10] += w22.z * hj2; acc[11] += w22.w * hj2;
    acc[12] += w23.x * hj2; acc[13] += w23.y * hj2; acc[14] += w23.z * hj2; acc[15] += w23.w * hj2;
    acc[0] += w30.x * hj3; acc[1] += w30.y * hj3; acc[2] += w30.z * hj3; acc[3] += w30.w * hj3;
    acc[4] += w31.x * hj3; acc[5] += w31.y * hj3; acc[6] += w31.z * hj3; acc[7] += w31.w * hj3;
    acc[8] += w32.x * hj3; acc[9] += w32.y * hj3; acc[10] += w32.z * hj3; acc[11] += w32.w * hj3;
    acc[12] += w33.x * hj3; acc[13] += w33.y * hj3; acc[14] += w33.z * hj3; acc[15] += w33.w * hj3;
  }
  for (; e < end; e++) {
    int j = __builtin_amdgcn_readfirstlane(p.src[e]);
    float hr = hpre[(size_t)j * WIDTH + lane];
    const float4* w4 = (const float4*)(p.wbuf + (size_t)e * KDIM);
    float4 w0 = w4[0], w1 = w4[1], w2 = w4[2], w3 = w4[3];
    float hj = lrelu(hr * scH + shH, SLOPE);
    acc[0] += w0.x * hj; acc[1] += w0.y * hj; acc[2] += w0.z * hj; acc[3] += w0.w * hj;
    acc[4] += w1.x * hj; acc[5] += w1.y * hj; acc[6] += w1.z * hj; acc[7] += w1.w * hj;
    acc[8] += w2.x * hj; acc[9] += w2.y * hj; acc[10] += w2.z * hj; acc[11] += w2.w * hj;
    acc[12] += w3.x * hj; acc[13] += w3.y * hj; acc[14] += w3.z * hj; acc[15] += w3.w * hj;
  }

#pragma unroll
  for (int k = 0; k < KDIM; k++) lds[wv * STRIP + k * ALD + lane] = acc[k];
  __syncthreads();

  // epilogue: out[n0+r][o] = sum_{k,c} agg[r][k][c] * Wf[(k*64+c)*O + o]
  int O = p.O;
  int o = t & (O - 1);
  int q = t / O;                       // O=32: 8 groups x kpg=2; O=16: 16 x 1
  int kpg = O >> 4;
  float part[4] = {0.f, 0.f, 0.f, 0.f};
  for (int kk = 0; kk < kpg; kk++) {
    int k = q * kpg + kk;
    const float* wf = p.Wf + (size_t)(k * WIDTH) * O + o;
    for (int c = 0; c < WIDTH; c += 4) {
      float w0 = wf[(size_t)(c + 0) * O];
      float w1 = wf[(size_t)(c + 1) * O];
      float w2 = wf[(size_t)(c + 2) * O];
      float w3 = wf[(size_t)(c + 3) * O];
#pragma unroll
      for (int r = 0; r < 4; r++) {
        float4 a = *(const float4*)(lds + r * STRIP + k * ALD + c);
        part[r] += a.x * w0 + a.y * w1 + a.z * w2 + a.w * w3;
      }
    }
  }
  for (int m = O; m < 64; m <<= 1) {
#pragma unroll
    for (int r = 0; r < 4; r++) part[r] += __shfl_xor(part[r], m, 64);
  }
  if (lane < O) {
#pragma unroll
    for (int r = 0; r < 4; r++) pw[wv][r][lane] = part[r];
  }
  __syncthreads();
  if (t < 4 * O) {
    int r = t / O, o2 = t % O;
    float v = pw[0][r][o2] + pw[1][r][o2] + pw[2][r][o2] + pw[3][r][o2];
    cat[(size_t)(n0 + r) * WIDTH + p.coloff + o2] = v;
    atomicAdd(&accum[128 + p.coloff + o2], v);         // outS
    atomicAdd(&accum[192 + p.coloff + o2], v * v);     // outQ
  }
}

// ============ final: out = lrelu(bn(cat))@outW + ident; 8 nodes/block =======
__global__ __launch_bounds__(256) void final_kernel(
    const float* __restrict__ cat,
    const float* __restrict__ out_g, const float* __restrict__ out_b,
    const float* __restrict__ accum,
    const float* __restrict__ outW,
    const float* __restrict__ identity, float* __restrict__ out)
{
  int t = threadIdx.x;
  int n0 = blockIdx.x * 8;
  __shared__ float sC[WIDTH], hC[WIDTH];
  __shared__ float cn8[8 * WIDTH];
  if (t < WIDTH) {
    float m = accum[128 + t] * (1.f / N_NODES);
    float v = accum[192 + t] * (1.f / N_NODES) - m * m;
    float s = out_g[t] * rsqrtf(v + BN_EPS);
    sC[t] = s; hC[t] = out_b[t] - m * s;
  }
  __syncthreads();
#pragma unroll
  for (int s = 0; s < 2; s++) {
    int ii = s * 256 + t;
    int r = ii >> 6, k = ii & 63;
    cn8[ii] = lrelu(cat[(size_t)(n0 + r) * WIDTH + k] * sC[k] + hC[k], SLOPE);
  }
  __syncthreads();
  float acc[8];
#pragma unroll
  for (int r = 0; r < 8; r++) acc[r] = identity[(size_t)(n0 + r) * COUT + t];
  for (int k = 0; k < WIDTH; k += 4) {
    float w0 = outW[(size_t)(k + 0) * COUT + t];
    float w1 = outW[(size_t)(k + 1) * COUT + t];
    float w2 = outW[(size_t)(k + 2) * COUT + t];
    float w3 = outW[(size_t)(k + 3) * COUT + t];
#pragma unroll
    for (int r = 0; r < 8; r++) {
      float4u a = *(const float4u*)(cn8 + r * WIDTH + k);
      acc[r] += a.x * w0 + a.y * w1 + a.z * w2 + a.w * w3;
    }
  }
#pragma unroll
  for (int r = 0; r < 8; r++) out[(size_t)(n0 + r) * COUT + t] = acc[r];
}

extern "C" void kernel_launch(void* const* d_in, const int* in_sizes, int n_in,
                              void* d_out, int out_size, void* d_ws, size_t ws_size,
                              hipStream_t stream) {
  const float* x    = (const float*)d_in[0];
  const float* pos  = (const float*)d_in[1];
  const float* ori  = (const float*)d_in[2];
  const int* seq  = (const int*)d_in[3];
  const int* src1 = (const int*)d_in[5];  const int* dst1 = (const int*)d_in[6];
  const int* src2 = (const int*)d_in[7];  const int* dst2 = (const int*)d_in[8];
  const int* src3 = (const int*)d_in[9];  const int* dst3 = (const int*)d_in[10];
  const float* id_g  = (const float*)d_in[11]; const float* id_b  = (const float*)d_in[12];
  const float* id_W  = (const float*)d_in[13];
  const float* in_g  = (const float*)d_in[14]; const float* in_b  = (const float*)d_in[15];
  const float* in_W  = (const float*)d_in[16];
  const float* mid_g = (const float*)d_in[17]; const float* mid_b = (const float*)d_in[18];
  const float* Ws1   = (const float*)d_in[19]; const float* bs1   = (const float*)d_in[20];
  const float* W1    = (const float*)d_in[21];
  const float* Ws2   = (const float*)d_in[22]; const float* bs2   = (const float*)d_in[23];
  const float* W2    = (const float*)d_in[24];
  const float* Ws3   = (const float*)d_in[25]; const float* bs3   = (const float*)d_in[26];
  const float* W3    = (const float*)d_in[27];
  const float* out_g = (const float*)d_in[28]; const float* out_b = (const float*)d_in[29];
  const float* out_W = (const float*)d_in[30];

  const int E1 = in_sizes[5], E2 = in_sizes[7], E3 = in_sizes[9];

  float* wsp = (float*)d_ws;
  size_t off = 0;
  auto alloc = [&](size_t n) { float* p = wsp + off; off += (n + 63) & ~(size_t)63; return p; };
  float* accum = alloc(256);                 // [midS|midQ|outS|outQ]
  float* sA   = alloc(CIN);   float* hA = alloc(CIN);
  float* sB   = alloc(CIN);   float* hB = alloc(CIN);
  float* ident = alloc((size_t)N_NODES * COUT);
  float* hpre  = alloc((size_t)N_NODES * WIDTH);
  float* catb  = alloc((size_t)N_NODES * WIDTH);
  int*   rowp  = (int*)alloc(3 * (N_NODES + 1));
  float* w1    = alloc((size_t)E1 * KDIM);
  float* w2    = alloc((size_t)E2 * KDIM);
  float* w3    = alloc((size_t)E3 * KDIM);
  (void)ws_size; (void)n_in; (void)out_size;

  int nb1 = (E1 + 255) / 256, nb2 = (E2 + 255) / 256, nb3 = (E3 + 255) / 256;

  EdgeP e0{src1, dst1, Ws1, bs1, w1, E1, 1.0f / 2.70f, 2};
  EdgeP e1{src2, dst2, Ws2, bs2, w2, E2, 1.0f / 1.80f, 3};
  EdgeP e2{src3, dst3, Ws3, bs3, w3, E3, 1.0f / 1.35f, 5};

  // 1. prep: zero accums | x-stats(+affines) | rowptr | edge gate weights
  prep_kernel<<<NB_STATSX + NB_ROWPTR + nb1 + nb2 + nb3, 256, 0, stream>>>(
      x, id_g, id_b, in_g, in_b, sA, hA, sB, hB, rowp, accum,
      e0, e1, e2, pos, ori, seq, nb1, nb2);
  // 2. both input GEMMs (fused BN+lrelu) + mid-BN sums
  gemm2_kernel<<<1024, 256, 0, stream>>>(x, sA, hA, sB, hB, id_W, in_W, ident, hpre, accum);
  // 3. fused aggregation + branch GEMMs (mid-BN affine inline) + out-BN sums
  AggP a0{src1, w1, W1, 32, 0};
  AggP a1{src2, w2, W2, 16, 32};
  AggP a2{src3, w3, W3, 16, 48};
  agg3_kernel<<<dim3(N_NODES / 4, 3), 256, 0, stream>>>(a0, a1, a2, rowp, hpre,
                                                        mid_g, mid_b, accum, catb);
  // 4. final GEMM + residual (out-BN affine inline)
  final_kernel<<<N_NODES / 8, 256, 0, stream>>>(catb, out_g, out_b, accum, out_W,
                                                ident, (float*)d_out);
}

// Round 9
// 233.014 us; speedup vs baseline: 2.2730x; 2.2730x over previous
//
#include <hip/hip_runtime.h>

#define N_NODES 4096
#define CIN     128
#define COUT    256
#define WIDTH   64
#define KDIM    16
#define SLOPE   0.1f
#define WSLOPE  0.2f
#define BN_EPS  1e-5f
#define NSTRIPE 32
// accum[NSTRIPE][256]: per stripe [midS 64 | midQ 64 | outS 64 | outQ 64]

typedef float float4u __attribute__((ext_vector_type(4), aligned(4)));

__device__ __forceinline__ float lrelu(float x, float s) { return x > 0.f ? x : s * x; }

// ======================= prep: stats_x + rowptr + edge_w =====================
struct EdgeP {
  const int* src; const int* dst;
  const float* Ws; const float* bs;
  float* wbuf; int E; float inv_r; int hl;
};

#define WS_LD 113
#define BS_LD 17
#define NB_STATSX 32
#define NB_ROWPTR 49

__global__ __launch_bounds__(256) void prep_kernel(
    const float* __restrict__ x,
    const float* __restrict__ id_g, const float* __restrict__ id_b,
    const float* __restrict__ in_g, const float* __restrict__ in_b,
    float* __restrict__ sA, float* __restrict__ hA,
    float* __restrict__ sB, float* __restrict__ hB,
    int* __restrict__ rowp, float* __restrict__ accum,
    EdgeP e0, EdgeP e1, EdgeP e2,
    const float* __restrict__ pos, const float* __restrict__ ori,
    const int* __restrict__ seq,
    int nb1, int nb2)
{
  int bx = blockIdx.x, t = threadIdx.x;

  if (bx < NB_STATSX) {
    accum[bx * 256 + t] = 0.f;           // zero this block's accum stripe
    // ---- column stats of x (4 channels per block) + both affines ----
    int cg = bx;
    int lane = t & 63, wv = t >> 6;
    float s[4] = {0.f, 0.f, 0.f, 0.f}, q[4] = {0.f, 0.f, 0.f, 0.f};
    for (int r = t; r < N_NODES; r += 256) {
      float4u a = *(const float4u*)(x + (size_t)r * CIN + cg * 4);
      float v[4] = {a.x, a.y, a.z, a.w};
#pragma unroll
      for (int i = 0; i < 4; i++) { s[i] += v[i]; q[i] += v[i] * v[i]; }
    }
#pragma unroll
    for (int m = 1; m < 64; m <<= 1) {
#pragma unroll
      for (int i = 0; i < 4; i++) { s[i] += __shfl_xor(s[i], m, 64); q[i] += __shfl_xor(q[i], m, 64); }
    }
    __shared__ float rs[4][4], rq[4][4];
    if (lane == 0) {
#pragma unroll
      for (int i = 0; i < 4; i++) { rs[wv][i] = s[i]; rq[wv][i] = q[i]; }
    }
    __syncthreads();
    if (t < 4) {
      float S = rs[0][t] + rs[1][t] + rs[2][t] + rs[3][t];
      float Q = rq[0][t] + rq[1][t] + rq[2][t] + rq[3][t];
      float m = S / N_NODES;
      float v = Q / N_NODES - m * m;
      float rsv = rsqrtf(v + BN_EPS);
      int c = cg * 4 + t;
      float sa = id_g[c] * rsv;
      float sb = in_g[c] * rsv;
      sA[c] = sa; hA[c] = id_b[c] - m * sa;
      sB[c] = sb; hB[c] = in_b[c] - m * sb;
    }
    return;
  }

  if (bx < NB_STATSX + NB_ROWPTR) {
    int idx = (bx - NB_STATSX) * 256 + t;
    if (idx >= 3 * (N_NODES + 1)) return;
    int b = idx / (N_NODES + 1);
    int n = idx % (N_NODES + 1);
    const int* d = (b == 0) ? e0.dst : (b == 1) ? e1.dst : e2.dst;
    int E = (b == 0) ? e0.E : (b == 1) ? e1.E : e2.E;
    int lo = 0, hi = E;
    if (n >= N_NODES) lo = E;
    else {
      while (lo < hi) { int mid = (lo + hi) >> 1; if (d[mid] < n) lo = mid + 1; else hi = mid; }
    }
    rowp[(size_t)b * (N_NODES + 1) + n] = lo;
    return;
  }

  // ---- per-edge gate weights ----
  int eb = bx - (NB_STATSX + NB_ROWPTR);
  EdgeP p;
  int base;
  if (eb < nb1)            { p = e0; base = eb; }
  else if (eb < nb1 + nb2) { p = e1; base = eb - nb1; }
  else                     { p = e2; base = eb - nb1 - nb2; }

  __shared__ float wsl[11 * WS_LD];
  __shared__ float bsl[11 * BS_LD];
  int L = 2 * p.hl + 1;
  for (int i = t; i < L * 112; i += 256) {
    int bin = i / 112, r = i - bin * 112;
    wsl[bin * WS_LD + r] = p.Ws[(size_t)bin * 112 + r];
  }
  for (int i = t; i < L * 16; i += 256) {
    int bin = i >> 4, r = i & 15;
    bsl[bin * BS_LD + r] = p.bs[(size_t)bin * 16 + r];
  }
  __syncthreads();

  int e = base * 256 + t;
  if (e >= p.E) return;
  int j = p.src[e], i = p.dst[e];
  float px = pos[j * 3 + 0] - pos[i * 3 + 0];
  float py = pos[j * 3 + 1] - pos[i * 3 + 1];
  float pz = pos[j * 3 + 2] - pos[i * 3 + 2];
  float fi[9], fj[9];
  {
    float4u a0 = *(const float4u*)(ori + (size_t)i * 9);
    float4u a1 = *(const float4u*)(ori + (size_t)i * 9 + 4);
    fi[0] = a0.x; fi[1] = a0.y; fi[2] = a0.z; fi[3] = a0.w;
    fi[4] = a1.x; fi[5] = a1.y; fi[6] = a1.z; fi[7] = a1.w;
    fi[8] = ori[(size_t)i * 9 + 8];
    float4u b0 = *(const float4u*)(ori + (size_t)j * 9);
    float4u b1 = *(const float4u*)(ori + (size_t)j * 9 + 4);
    fj[0] = b0.x; fj[1] = b0.y; fj[2] = b0.z; fj[3] = b0.w;
    fj[4] = b1.x; fj[5] = b1.y; fj[6] = b1.z; fj[7] = b1.w;
    fj[8] = ori[(size_t)j * 9 + 8];
  }
  float dist = sqrtf(px * px + py * py + pz * pz);
  float inv = 1.0f / (dist + 1e-9f);
  float dx = px * inv, dy = py * inv, dz = pz * inv;
  float feat[7];
  feat[0] = dist * p.inv_r;
  feat[1] = fi[0] * dx + fi[1] * dy + fi[2] * dz;
  feat[2] = fi[3] * dx + fi[4] * dy + fi[5] * dz;
  feat[3] = fi[6] * dx + fi[7] * dy + fi[8] * dz;
  feat[4] = fi[0] * fj[0] + fi[1] * fj[1] + fi[2] * fj[2];
  feat[5] = fi[3] * fj[3] + fi[4] * fj[4] + fi[5] * fj[5];
  feat[6] = fi[6] * fj[6] + fi[7] * fj[7] + fi[8] * fj[8];
  int d = seq[j] - seq[i];
  d = d < -p.hl ? -p.hl : (d > p.hl ? p.hl : d);
  int bin = d + p.hl;
  const float* Wp = wsl + bin * WS_LD;
  const float* bp = bsl + bin * BS_LD;
  float w16[KDIM];
#pragma unroll
  for (int k = 0; k < KDIM; k++) {
    float a = bp[k];
#pragma unroll
    for (int c = 0; c < 7; c++) a += feat[c] * Wp[c * KDIM + k];
    w16[k] = lrelu(a, WSLOPE);
  }
  float4* wb = (float4*)(p.wbuf + (size_t)e * KDIM);
#pragma unroll
  for (int k = 0; k < 4; k++)
    wb[k] = make_float4(w16[4 * k], w16[4 * k + 1], w16[4 * k + 2], w16[4 * k + 3]);
}

// =========== gemm2: ident = act_id(x)@id_W | hpre = act_in(x)@in_W ==========
__global__ __launch_bounds__(256) void gemm2_kernel(
    const float* __restrict__ x,
    const float* __restrict__ sA, const float* __restrict__ hA,
    const float* __restrict__ sB, const float* __restrict__ hB,
    const float* __restrict__ idW, const float* __restrict__ inW,
    float* __restrict__ ident, float* __restrict__ hpre,
    float* __restrict__ accum)
{
  int bx = blockIdx.x, t = threadIdx.x;
  __shared__ float at[8 * CIN];   // 4 KB, bn+lrelu applied
  bool coutp = bx < 512;
  int n0 = (coutp ? bx : bx - 512) * 8;
  {
    int r = t >> 5, c4 = (t & 31) * 4;
    const float* S = coutp ? sA : sB;
    const float* H = coutp ? hA : hB;
    float4u xv = *(const float4u*)(x + (size_t)(n0 + r) * CIN + c4);
    float4u sv = *(const float4u*)(S + c4);
    float4u hv = *(const float4u*)(H + c4);
    float4u o;
    o.x = lrelu(xv.x * sv.x + hv.x, SLOPE);
    o.y = lrelu(xv.y * sv.y + hv.y, SLOPE);
    o.z = lrelu(xv.z * sv.z + hv.z, SLOPE);
    o.w = lrelu(xv.w * sv.w + hv.w, SLOPE);
    *(float4u*)(at + r * CIN + c4) = o;
  }
  __syncthreads();
  if (coutp) {
    float acc[8] = {0.f, 0.f, 0.f, 0.f, 0.f, 0.f, 0.f, 0.f};
    for (int k = 0; k < CIN; k += 4) {
      float w0 = idW[(size_t)(k + 0) * COUT + t];
      float w1 = idW[(size_t)(k + 1) * COUT + t];
      float w2 = idW[(size_t)(k + 2) * COUT + t];
      float w3 = idW[(size_t)(k + 3) * COUT + t];
#pragma unroll
      for (int r8 = 0; r8 < 8; r8++) {
        float4u a = *(const float4u*)(at + r8 * CIN + k);
        acc[r8] += a.x * w0 + a.y * w1 + a.z * w2 + a.w * w3;
      }
    }
#pragma unroll
    for (int r8 = 0; r8 < 8; r8++) ident[(size_t)(n0 + r8) * COUT + t] = acc[r8];
  } else {
    int j = t & 63, g = t >> 6;
    float a0 = 0.f, a1 = 0.f;
    for (int k = 0; k < CIN; k += 4) {
      float w0 = inW[(size_t)(k + 0) * WIDTH + j];
      float w1 = inW[(size_t)(k + 1) * WIDTH + j];
      float w2 = inW[(size_t)(k + 2) * WIDTH + j];
      float w3 = inW[(size_t)(k + 3) * WIDTH + j];
      float4u u = *(const float4u*)(at + (2 * g) * CIN + k);
      float4u v = *(const float4u*)(at + (2 * g + 1) * CIN + k);
      a0 += u.x * w0 + u.y * w1 + u.z * w2 + u.w * w3;
      a1 += v.x * w0 + v.y * w1 + v.z * w2 + v.w * w3;
    }
    hpre[(size_t)(n0 + 2 * g) * WIDTH + j] = a0;
    hpre[(size_t)(n0 + 2 * g + 1) * WIDTH + j] = a1;
    // ---- mid-BN partial sums: block-reduce, then striped atomics ----
    __shared__ float ps[4][WIDTH], pq[4][WIDTH];
    ps[g][j] = a0 + a1;
    pq[g][j] = a0 * a0 + a1 * a1;
    __syncthreads();
    if (t < WIDTH) {
      float* as = accum + (bx & (NSTRIPE - 1)) * 256;
      atomicAdd(&as[t],      ps[0][t] + ps[1][t] + ps[2][t] + ps[3][t]);
      atomicAdd(&as[64 + t], pq[0][t] + pq[1][t] + pq[2][t] + pq[3][t]);
    }
  }
}

// ====== agg3: round-7 core (1 node/block, 4 waves split edges, unroll x4) ====
struct AggP {
  const int* src; const float* wbuf; const float* Wf;
  int O; int coloff;
};

#define ALD 68   // padded k-row stride

__global__ __launch_bounds__(256) void agg3_kernel(
    AggP p0, AggP p1, AggP p2, const int* __restrict__ rowp,
    const float* __restrict__ hpre,
    const float* __restrict__ mid_g, const float* __restrict__ mid_b,
    float* __restrict__ accum, float* __restrict__ cat)
{
  int b = blockIdx.y;
  AggP p = (b == 0) ? p0 : (b == 1) ? p1 : p2;
  int n = blockIdx.x, t = threadIdx.x, lane = t & 63, wv = t >> 6;

  __shared__ float lds[4][KDIM * ALD];
  __shared__ float pw[4][WIDTH];
  __shared__ float sHl[WIDTH], hHl[WIDTH];
  if (t < WIDTH) {
    float S = 0.f, Q = 0.f;
#pragma unroll
    for (int s = 0; s < NSTRIPE; s++) {
      S += accum[s * 256 + t];
      Q += accum[s * 256 + 64 + t];
    }
    float m = S * (1.f / N_NODES);
    float v = Q * (1.f / N_NODES) - m * m;
    float sc = mid_g[t] * rsqrtf(v + BN_EPS);
    sHl[t] = sc; hHl[t] = mid_b[t] - m * sc;
  }
  __syncthreads();
  float scH = sHl[lane], shH = hHl[lane];

  const int* rp = rowp + (size_t)b * (N_NODES + 1);
  int start = rp[n], end = rp[n + 1];

  float acc[KDIM];
#pragma unroll
  for (int k = 0; k < KDIM; k++) acc[k] = 0.f;

  int e = start + wv;
  for (; e + 12 < end; e += 16) {
    int j0 = __builtin_amdgcn_readfirstlane(p.src[e]);
    int j1 = __builtin_amdgcn_readfirstlane(p.src[e + 4]);
    int j2 = __builtin_amdgcn_readfirstlane(p.src[e + 8]);
    int j3 = __builtin_amdgcn_readfirstlane(p.src[e + 12]);
    float r0 = hpre[(size_t)j0 * WIDTH + lane];
    float r1 = hpre[(size_t)j1 * WIDTH + lane];
    float r2 = hpre[(size_t)j2 * WIDTH + lane];
    float r3 = hpre[(size_t)j3 * WIDTH + lane];
    const float4* a0 = (const float4*)(p.wbuf + (size_t)e * KDIM);
    const float4* a1 = (const float4*)(p.wbuf + (size_t)(e + 4) * KDIM);
    const float4* a2 = (const float4*)(p.wbuf + (size_t)(e + 8) * KDIM);
    const float4* a3 = (const float4*)(p.wbuf + (size_t)(e + 12) * KDIM);
    float4 w00 = a0[0], w01 = a0[1], w02 = a0[2], w03 = a0[3];
    float4 w10 = a1[0], w11 = a1[1], w12 = a1[2], w13 = a1[3];
    float4 w20 = a2[0], w21 = a2[1], w22 = a2[2], w23 = a2[3];
    float4 w30 = a3[0], w31 = a3[1], w32 = a3[2], w33 = a3[3];
    float hj0 = lrelu(r0 * scH + shH, SLOPE);
    float hj1 = lrelu(r1 * scH + shH, SLOPE);
    float hj2 = lrelu(r2 * scH + shH, SLOPE);
    float hj3 = lrelu(r3 * scH + shH, SLOPE);
    acc[0] += w00.x * hj0; acc[1] += w00.y * hj0; acc[2] += w00.z * hj0; acc[3] += w00.w * hj0;
    acc[4] += w01.x * hj0; acc[5] += w01.y * hj0; acc[6] += w01.z * hj0; acc[7] += w01.w * hj0;
    acc[8] += w02.x * hj0; acc[9] += w02.y * hj0; acc[10] += w02.z * hj0; acc[11] += w02.w * hj0;
    acc[12] += w03.x * hj0; acc[13] += w03.y * hj0; acc[14] += w03.z * hj0; acc[15] += w03.w * hj0;
    acc[0] += w10.x * hj1; acc[1] += w10.y * hj1; acc[2] += w10.z * hj1; acc[3] += w10.w * hj1;
    acc[4] += w11.x * hj1; acc[5] += w11.y * hj1; acc[6] += w11.z * hj1; acc[7] += w11.w * hj1;
    acc[8] += w12.x * hj1; acc[9] += w12.y * hj1; acc[10] += w12.z * hj1; acc[11] += w12.w * hj1;
    acc[12] += w13.x * hj1; acc[13] += w13.y * hj1; acc[14] += w13.z * hj1; acc[15] += w13.w * hj1;
    acc[0] += w20.x * hj2; acc[1] += w20.y * hj2; acc[2] += w20.z * hj2; acc[3] += w20.w * hj2;
    acc[4] += w21.x * hj2; acc[5] += w21.y * hj2; acc[6] += w21.z * hj2; acc[7] += w21.w * hj2;
    acc[8] += w22.x * hj2; acc[9] += w22.y * hj2; acc[10] += w22.z * hj2; acc[11] += w22.w * hj2;
    acc[12] += w23.x * hj2; acc[13] += w23.y * hj2; acc[14] += w23.z * hj2; acc[15] += w23.w * hj2;
    acc[0] += w30.x * hj3; acc[1] += w30.y * hj3; acc[2] += w30.z * hj3; acc[3] += w30.w * hj3;
    acc[4] += w31.x * hj3; acc[5] += w31.y * hj3; acc[6] += w31.z * hj3; acc[7] += w31.w * hj3;
    acc[8] += w32.x * hj3; acc[9] += w32.y * hj3; acc[10] += w32.z * hj3; acc[11] += w32.w * hj3;
    acc[12] += w33.x * hj3; acc[13] += w33.y * hj3; acc[14] += w33.z * hj3; acc[15] += w33.w * hj3;
  }
  for (; e < end; e += 4) {
    int j = __builtin_amdgcn_readfirstlane(p.src[e]);
    float hr = hpre[(size_t)j * WIDTH + lane];
    const float4* w4 = (const float4*)(p.wbuf + (size_t)e * KDIM);
    float4 w0 = w4[0], w1 = w4[1], w2 = w4[2], w3 = w4[3];
    float hj = lrelu(hr * scH + shH, SLOPE);
    acc[0] += w0.x * hj; acc[1] += w0.y * hj; acc[2] += w0.z * hj; acc[3] += w0.w * hj;
    acc[4] += w1.x * hj; acc[5] += w1.y * hj; acc[6] += w1.z * hj; acc[7] += w1.w * hj;
    acc[8] += w2.x * hj; acc[9] += w2.y * hj; acc[10] += w2.z * hj; acc[11] += w2.w * hj;
    acc[12] += w3.x * hj; acc[13] += w3.y * hj; acc[14] += w3.z * hj; acc[15] += w3.w * hj;
  }

#pragma unroll
  for (int k = 0; k < KDIM; k++) lds[wv][k * ALD + lane] = acc[k];
  __syncthreads();

  for (int i = t; i < KDIM * ALD; i += 256)
    lds[0][i] = lds[0][i] + lds[1][i] + lds[2][i] + lds[3][i];
  __syncthreads();

  int O = p.O;
  int o = t & (O - 1);
  int q = t / O;
  int kpg = O >> 4;
  float part = 0.f;
  for (int kk = 0; kk < kpg; kk++) {
    int k = q * kpg + kk;
    const float* ar = lds[0] + k * ALD;
    const float* wf = p.Wf + (size_t)(k * WIDTH) * O + o;
    for (int c = 0; c < WIDTH; c += 4) {
      float4 a = *(const float4*)(ar + c);
      part += a.x * wf[(size_t)(c + 0) * O];
      part += a.y * wf[(size_t)(c + 1) * O];
      part += a.z * wf[(size_t)(c + 2) * O];
      part += a.w * wf[(size_t)(c + 3) * O];
    }
  }
  for (int m = O; m < 64; m <<= 1) part += __shfl_xor(part, m, 64);
  if (lane < O) pw[wv][lane] = part;
  __syncthreads();
  if (t < O) {
    float v = pw[0][t] + pw[1][t] + pw[2][t] + pw[3][t];
    cat[(size_t)n * WIDTH + p.coloff + t] = v;
    float* as = accum + (n & (NSTRIPE - 1)) * 256;
    atomicAdd(&as[128 + p.coloff + t], v);
    atomicAdd(&as[192 + p.coloff + t], v * v);
  }
}

// ============ final: out = lrelu(bn(cat))@outW + ident; 8 nodes/block =======
__global__ __launch_bounds__(256) void final_kernel(
    const float* __restrict__ cat,
    const float* __restrict__ out_g, const float* __restrict__ out_b,
    const float* __restrict__ accum,
    const float* __restrict__ outW,
    const float* __restrict__ identity, float* __restrict__ out)
{
  int t = threadIdx.x;
  int n0 = blockIdx.x * 8;
  __shared__ float sC[WIDTH], hC[WIDTH];
  __shared__ float cn8[8 * WIDTH];
  if (t < WIDTH) {
    float S = 0.f, Q = 0.f;
#pragma unroll
    for (int s = 0; s < NSTRIPE; s++) {
      S += accum[s * 256 + 128 + t];
      Q += accum[s * 256 + 192 + t];
    }
    float m = S * (1.f / N_NODES);
    float v = Q * (1.f / N_NODES) - m * m;
    float sc = out_g[t] * rsqrtf(v + BN_EPS);
    sC[t] = sc; hC[t] = out_b[t] - m * sc;
  }
  __syncthreads();
#pragma unroll
  for (int s = 0; s < 2; s++) {
    int ii = s * 256 + t;
    int r = ii >> 6, k = ii & 63;
    cn8[ii] = lrelu(cat[(size_t)(n0 + r) * WIDTH + k] * sC[k] + hC[k], SLOPE);
  }
  __syncthreads();
  float acc[8];
#pragma unroll
  for (int r = 0; r < 8; r++) acc[r] = identity[(size_t)(n0 + r) * COUT + t];
  for (int k = 0; k < WIDTH; k += 4) {
    float w0 = outW[(size_t)(k + 0) * COUT + t];
    float w1 = outW[(size_t)(k + 1) * COUT + t];
    float w2 = outW[(size_t)(k + 2) * COUT + t];
    float w3 = outW[(size_t)(k + 3) * COUT + t];
#pragma unroll
    for (int r = 0; r < 8; r++) {
      float4u a = *(const float4u*)(cn8 + r * WIDTH + k);
      acc[r] += a.x * w0 + a.y * w1 + a.z * w2 + a.w * w3;
    }
  }
#pragma unroll
  for (int r = 0; r < 8; r++) out[(size_t)(n0 + r) * COUT + t] = acc[r];
}

extern "C" void kernel_launch(void* const* d_in, const int* in_sizes, int n_in,
                              void* d_out, int out_size, void* d_ws, size_t ws_size,
                              hipStream_t stream) {
  const float* x    = (const float*)d_in[0];
  const float* pos  = (const float*)d_in[1];
  const float* ori  = (const float*)d_in[2];
  const int* seq  = (const int*)d_in[3];
  const int* src1 = (const int*)d_in[5];  const int* dst1 = (const int*)d_in[6];
  const int* src2 = (const int*)d_in[7];  const int* dst2 = (const int*)d_in[8];
  const int* src3 = (const int*)d_in[9];  const int* dst3 = (const int*)d_in[10];
  const float* id_g  = (const float*)d_in[11]; const float* id_b  = (const float*)d_in[12];
  const float* id_W  = (const float*)d_in[13];
  const float* in_g  = (const float*)d_in[14]; const float* in_b  = (const float*)d_in[15];
  const float* in_W  = (const float*)d_in[16];
  const float* mid_g = (const float*)d_in[17]; const float* mid_b = (const float*)d_in[18];
  const float* Ws1   = (const float*)d_in[19]; const float* bs1   = (const float*)d_in[20];
  const float* W1    = (const float*)d_in[21];
  const float* Ws2   = (const float*)d_in[22]; const float* bs2   = (const float*)d_in[23];
  const float* W2    = (const float*)d_in[24];
  const float* Ws3   = (const float*)d_in[25]; const float* bs3   = (const float*)d_in[26];
  const float* W3    = (const float*)d_in[27];
  const float* out_g = (const float*)d_in[28]; const float* out_b = (const float*)d_in[29];
  const float* out_W = (const float*)d_in[30];

  const int E1 = in_sizes[5], E2 = in_sizes[7], E3 = in_sizes[9];

  float* wsp = (float*)d_ws;
  size_t off = 0;
  auto alloc = [&](size_t n) { float* p = wsp + off; off += (n + 63) & ~(size_t)63; return p; };
  float* accum = alloc(NSTRIPE * 256);       // striped [midS|midQ|outS|outQ]
  float* sA   = alloc(CIN);   float* hA = alloc(CIN);
  float* sB   = alloc(CIN);   float* hB = alloc(CIN);
  float* ident = alloc((size_t)N_NODES * COUT);
  float* hpre  = alloc((size_t)N_NODES * WIDTH);
  float* catb  = alloc((size_t)N_NODES * WIDTH);
  int*   rowp  = (int*)alloc(3 * (N_NODES + 1));
  float* w1    = alloc((size_t)E1 * KDIM);
  float* w2    = alloc((size_t)E2 * KDIM);
  float* w3    = alloc((size_t)E3 * KDIM);
  (void)ws_size; (void)n_in; (void)out_size;

  int nb1 = (E1 + 255) / 256, nb2 = (E2 + 255) / 256, nb3 = (E3 + 255) / 256;

  EdgeP e0{src1, dst1, Ws1, bs1, w1, E1, 1.0f / 2.70f, 2};
  EdgeP e1{src2, dst2, Ws2, bs2, w2, E2, 1.0f / 1.80f, 3};
  EdgeP e2{src3, dst3, Ws3, bs3, w3, E3, 1.0f / 1.35f, 5};

  // 1. prep: zero accum stripes | x-stats(+affines) | rowptr | edge weights
  prep_kernel<<<NB_STATSX + NB_ROWPTR + nb1 + nb2 + nb3, 256, 0, stream>>>(
      x, id_g, id_b, in_g, in_b, sA, hA, sB, hB, rowp, accum,
      e0, e1, e2, pos, ori, seq, nb1, nb2);
  // 2. both input GEMMs (fused BN+lrelu) + striped mid-BN sums
  gemm2_kernel<<<1024, 256, 0, stream>>>(x, sA, hA, sB, hB, id_W, in_W, ident, hpre, accum);
  // 3. aggregation + branch GEMMs (round-7 core) + striped out-BN sums
  AggP a0{src1, w1, W1, 32, 0};
  AggP a1{src2, w2, W2, 16, 32};
  AggP a2{src3, w3, W3, 16, 48};
  agg3_kernel<<<dim3(N_NODES, 3), 256, 0, stream>>>(a0, a1, a2, rowp, hpre,
                                                    mid_g, mid_b, accum, catb);
  // 4. final GEMM + residual (out-BN affine inline)
  final_kernel<<<N_NODES / 8, 256, 0, stream>>>(catb, out_g, out_b, accum, out_W,
                                                ident, (float*)d_out);
}

// Round 11
// 221.416 us; speedup vs baseline: 2.3921x; 1.0524x over previous
//
#include <hip/hip_runtime.h>

#define N_NODES 4096
#define CIN     128
#define COUT    256
#define WIDTH   64
#define KDIM    16
#define SLOPE   0.1f
#define WSLOPE  0.2f
#define BN_EPS  1e-5f

typedef float float4u __attribute__((ext_vector_type(4), aligned(4)));

__device__ __forceinline__ float lrelu(float x, float s) { return x > 0.f ? x : s * x; }

// ======================= prep: stats_x + rowptr + edge_w =====================
struct EdgeP {
  const int* src; const int* dst;
  const float* Ws; const float* bs;
  float* wbuf; int E; float inv_r; int hl;
};

#define WS_LD 113
#define BS_LD 17
#define NB_STATSX 32
#define NB_ROWPTR 49

__global__ __launch_bounds__(256) void prep_kernel(
    const float* __restrict__ x,
    const float* __restrict__ id_g, const float* __restrict__ id_b,
    const float* __restrict__ in_g, const float* __restrict__ in_b,
    float* __restrict__ sA, float* __restrict__ hA,
    float* __restrict__ sB, float* __restrict__ hB,
    int* __restrict__ rowp,
    EdgeP e0, EdgeP e1, EdgeP e2,
    const float* __restrict__ pos, const float* __restrict__ ori,
    const int* __restrict__ seq,
    int nb1, int nb2)
{
  int bx = blockIdx.x, t = threadIdx.x;

  if (bx < NB_STATSX) {
    int cg = bx;
    int lane = t & 63, wv = t >> 6;
    float s[4] = {0.f, 0.f, 0.f, 0.f}, q[4] = {0.f, 0.f, 0.f, 0.f};
    for (int r = t; r < N_NODES; r += 256) {
      float4u a = *(const float4u*)(x + (size_t)r * CIN + cg * 4);
      float v[4] = {a.x, a.y, a.z, a.w};
#pragma unroll
      for (int i = 0; i < 4; i++) { s[i] += v[i]; q[i] += v[i] * v[i]; }
    }
#pragma unroll
    for (int m = 1; m < 64; m <<= 1) {
#pragma unroll
      for (int i = 0; i < 4; i++) { s[i] += __shfl_xor(s[i], m, 64); q[i] += __shfl_xor(q[i], m, 64); }
    }
    __shared__ float rs[4][4], rq[4][4];
    if (lane == 0) {
#pragma unroll
      for (int i = 0; i < 4; i++) { rs[wv][i] = s[i]; rq[wv][i] = q[i]; }
    }
    __syncthreads();
    if (t < 4) {
      float S = rs[0][t] + rs[1][t] + rs[2][t] + rs[3][t];
      float Q = rq[0][t] + rq[1][t] + rq[2][t] + rq[3][t];
      float m = S / N_NODES;
      float v = Q / N_NODES - m * m;
      float rsv = rsqrtf(v + BN_EPS);
      int c = cg * 4 + t;
      float sa = id_g[c] * rsv;
      float sb = in_g[c] * rsv;
      sA[c] = sa; hA[c] = id_b[c] - m * sa;
      sB[c] = sb; hB[c] = in_b[c] - m * sb;
    }
    return;
  }

  if (bx < NB_STATSX + NB_ROWPTR) {
    int idx = (bx - NB_STATSX) * 256 + t;
    if (idx >= 3 * (N_NODES + 1)) return;
    int b = idx / (N_NODES + 1);
    int n = idx % (N_NODES + 1);
    const int* d = (b == 0) ? e0.dst : (b == 1) ? e1.dst : e2.dst;
    int E = (b == 0) ? e0.E : (b == 1) ? e1.E : e2.E;
    int lo = 0, hi = E;
    if (n >= N_NODES) lo = E;
    else {
      while (lo < hi) { int mid = (lo + hi) >> 1; if (d[mid] < n) lo = mid + 1; else hi = mid; }
    }
    rowp[(size_t)b * (N_NODES + 1) + n] = lo;
    return;
  }

  // ---- per-edge gate weights ----
  int eb = bx - (NB_STATSX + NB_ROWPTR);
  EdgeP p;
  int base;
  if (eb < nb1)            { p = e0; base = eb; }
  else if (eb < nb1 + nb2) { p = e1; base = eb - nb1; }
  else                     { p = e2; base = eb - nb1 - nb2; }

  __shared__ float wsl[11 * WS_LD];
  __shared__ float bsl[11 * BS_LD];
  int L = 2 * p.hl + 1;
  for (int i = t; i < L * 112; i += 256) {
    int bin = i / 112, r = i - bin * 112;
    wsl[bin * WS_LD + r] = p.Ws[(size_t)bin * 112 + r];
  }
  for (int i = t; i < L * 16; i += 256) {
    int bin = i >> 4, r = i & 15;
    bsl[bin * BS_LD + r] = p.bs[(size_t)bin * 16 + r];
  }
  __syncthreads();

  int e = base * 256 + t;
  if (e >= p.E) return;
  int j = p.src[e], i = p.dst[e];
  float px = pos[j * 3 + 0] - pos[i * 3 + 0];
  float py = pos[j * 3 + 1] - pos[i * 3 + 1];
  float pz = pos[j * 3 + 2] - pos[i * 3 + 2];
  float fi[9], fj[9];
  {
    float4u a0 = *(const float4u*)(ori + (size_t)i * 9);
    float4u a1 = *(const float4u*)(ori + (size_t)i * 9 + 4);
    fi[0] = a0.x; fi[1] = a0.y; fi[2] = a0.z; fi[3] = a0.w;
    fi[4] = a1.x; fi[5] = a1.y; fi[6] = a1.z; fi[7] = a1.w;
    fi[8] = ori[(size_t)i * 9 + 8];
    float4u b0 = *(const float4u*)(ori + (size_t)j * 9);
    float4u b1 = *(const float4u*)(ori + (size_t)j * 9 + 4);
    fj[0] = b0.x; fj[1] = b0.y; fj[2] = b0.z; fj[3] = b0.w;
    fj[4] = b1.x; fj[5] = b1.y; fj[6] = b1.z; fj[7] = b1.w;
    fj[8] = ori[(size_t)j * 9 + 8];
  }
  float dist = sqrtf(px * px + py * py + pz * pz);
  float inv = 1.0f / (dist + 1e-9f);
  float dx = px * inv, dy = py * inv, dz = pz * inv;
  float feat[7];
  feat[0] = dist * p.inv_r;
  feat[1] = fi[0] * dx + fi[1] * dy + fi[2] * dz;
  feat[2] = fi[3] * dx + fi[4] * dy + fi[5] * dz;
  feat[3] = fi[6] * dx + fi[7] * dy + fi[8] * dz;
  feat[4] = fi[0] * fj[0] + fi[1] * fj[1] + fi[2] * fj[2];
  feat[5] = fi[3] * fj[3] + fi[4] * fj[4] + fi[5] * fj[5];
  feat[6] = fi[6] * fj[6] + fi[7] * fj[7] + fi[8] * fj[8];
  int d = seq[j] - seq[i];
  d = d < -p.hl ? -p.hl : (d > p.hl ? p.hl : d);
  int bin = d + p.hl;
  const float* Wp = wsl + bin * WS_LD;
  const float* bp = bsl + bin * BS_LD;
  float w16[KDIM];
#pragma unroll
  for (int k = 0; k < KDIM; k++) {
    float a = bp[k];
#pragma unroll
    for (int c = 0; c < 7; c++) a += feat[c] * Wp[c * KDIM + k];
    w16[k] = lrelu(a, WSLOPE);
  }
  float4* wb = (float4*)(p.wbuf + (size_t)e * KDIM);
#pragma unroll
  for (int k = 0; k < 4; k++)
    wb[k] = make_float4(w16[4 * k], w16[4 * k + 1], w16[4 * k + 2], w16[4 * k + 3]);
}

// =========== gemm2: ident = act_id(x)@id_W  |  hpre = act_in(x)@in_W ========
__global__ __launch_bounds__(256) void gemm2_kernel(
    const float* __restrict__ x,
    const float* __restrict__ sA, const float* __restrict__ hA,
    const float* __restrict__ sB, const float* __restrict__ hB,
    const float* __restrict__ idW, const float* __restrict__ inW,
    float* __restrict__ ident, float* __restrict__ hpre)
{
  int bx = blockIdx.x, t = threadIdx.x;
  __shared__ float at[8 * CIN];   // 4 KB, bn+lrelu applied
  bool coutp = bx < 512;
  int n0 = (coutp ? bx : bx - 512) * 8;
  {
    int r = t >> 5, c4 = (t & 31) * 4;
    const float* S = coutp ? sA : sB;
    const float* H = coutp ? hA : hB;
    float4u xv = *(const float4u*)(x + (size_t)(n0 + r) * CIN + c4);
    float4u sv = *(const float4u*)(S + c4);
    float4u hv = *(const float4u*)(H + c4);
    float4u o;
    o.x = lrelu(xv.x * sv.x + hv.x, SLOPE);
    o.y = lrelu(xv.y * sv.y + hv.y, SLOPE);
    o.z = lrelu(xv.z * sv.z + hv.z, SLOPE);
    o.w = lrelu(xv.w * sv.w + hv.w, SLOPE);
    *(float4u*)(at + r * CIN + c4) = o;
  }
  __syncthreads();
  if (coutp) {
    float acc[8] = {0.f, 0.f, 0.f, 0.f, 0.f, 0.f, 0.f, 0.f};
    for (int k = 0; k < CIN; k += 4) {
      float w0 = idW[(size_t)(k + 0) * COUT + t];
      float w1 = idW[(size_t)(k + 1) * COUT + t];
      float w2 = idW[(size_t)(k + 2) * COUT + t];
      float w3 = idW[(size_t)(k + 3) * COUT + t];
#pragma unroll
      for (int r8 = 0; r8 < 8; r8++) {
        float4u a = *(const float4u*)(at + r8 * CIN + k);
        acc[r8] += a.x * w0 + a.y * w1 + a.z * w2 + a.w * w3;
      }
    }
#pragma unroll
    for (int r8 = 0; r8 < 8; r8++) ident[(size_t)(n0 + r8) * COUT + t] = acc[r8];
  } else {
    int j = t & 63, g = t >> 6;
    float a0 = 0.f, a1 = 0.f;
    for (int k = 0; k < CIN; k += 4) {
      float w0 = inW[(size_t)(k + 0) * WIDTH + j];
      float w1 = inW[(size_t)(k + 1) * WIDTH + j];
      float w2 = inW[(size_t)(k + 2) * WIDTH + j];
      float w3 = inW[(size_t)(k + 3) * WIDTH + j];
      float4u u = *(const float4u*)(at + (2 * g) * CIN + k);
      float4u v = *(const float4u*)(at + (2 * g + 1) * CIN + k);
      a0 += u.x * w0 + u.y * w1 + u.z * w2 + u.w * w3;
      a1 += v.x * w0 + v.y * w1 + v.z * w2 + v.w * w3;
    }
    hpre[(size_t)(n0 + 2 * g) * WIDTH + j] = a0;
    hpre[(size_t)(n0 + 2 * g + 1) * WIDTH + j] = a1;
  }
}

// ====== stats_affine: col stats of X[4096,C] -> s = g*rsqrt(v+eps), h = b-m*s
__global__ __launch_bounds__(256) void stats_affine_kernel(
    const float* __restrict__ X, int C,
    const float* __restrict__ g, const float* __restrict__ b,
    float* __restrict__ s_out, float* __restrict__ h_out)
{
  int cg = blockIdx.x;
  int t = threadIdx.x, lane = t & 63, wv = t >> 6;
  float s[4] = {0.f, 0.f, 0.f, 0.f}, q[4] = {0.f, 0.f, 0.f, 0.f};
  for (int r = t; r < N_NODES; r += 256) {
    float4u a = *(const float4u*)(X + (size_t)r * C + cg * 4);
    float v[4] = {a.x, a.y, a.z, a.w};
#pragma unroll
    for (int i = 0; i < 4; i++) { s[i] += v[i]; q[i] += v[i] * v[i]; }
  }
#pragma unroll
  for (int m = 1; m < 64; m <<= 1) {
#pragma unroll
    for (int i = 0; i < 4; i++) { s[i] += __shfl_xor(s[i], m, 64); q[i] += __shfl_xor(q[i], m, 64); }
  }
  __shared__ float rs[4][4], rq[4][4];
  if (lane == 0) {
#pragma unroll
    for (int i = 0; i < 4; i++) { rs[wv][i] = s[i]; rq[wv][i] = q[i]; }
  }
  __syncthreads();
  if (t < 4) {
    float S = rs[0][t] + rs[1][t] + rs[2][t] + rs[3][t];
    float Q = rq[0][t] + rq[1][t] + rq[2][t] + rq[3][t];
    float m = S / N_NODES;
    float v = Q / N_NODES - m * m;
    int c = cg * 4 + t;
    float sv = g[c] * rsqrtf(v + BN_EPS);
    s_out[c] = sv;
    h_out[c] = b[c] - m * sv;
  }
}

// ====== agg3: 2 nodes/block; wave-pairs split each node's edges; ============
// ====== epilogue shares each Wf load across both nodes (L2 traffic /2) ======
struct AggP {
  const int* src; const float* wbuf; const float* Wf;
  int O; int coloff;
};

#define ALD 68   // padded k-row stride

__global__ __launch_bounds__(256) void agg3_kernel(
    AggP p0, AggP p1, AggP p2, const int* __restrict__ rowp,
    const float* __restrict__ hpre,
    const float* __restrict__ sH, const float* __restrict__ hH,
    float* __restrict__ cat)
{
  int b = blockIdx.y;
  AggP p = (b == 0) ? p0 : (b == 1) ? p1 : p2;
  int nA = blockIdx.x * 2, t = threadIdx.x, lane = t & 63, wv = t >> 6;

  __shared__ float lds[4][KDIM * ALD];   // 17.4 KB
  __shared__ float pw[4][2][32];         // wave, node, col
  __shared__ float sHl[WIDTH], hHl[WIDTH];
  if (t < WIDTH) { sHl[t] = sH[t]; hHl[t] = hH[t]; }
  __syncthreads();
  float scH = sHl[lane], shH = hHl[lane];

  // waves 0,1 -> node A; waves 2,3 -> node B; each pair splits edges stride 2
  int n = nA + (wv >> 1);
  int sub = wv & 1;
  const int* rp = rowp + (size_t)b * (N_NODES + 1);
  int start = rp[n], end = rp[n + 1];

  float acc[KDIM];
#pragma unroll
  for (int k = 0; k < KDIM; k++) acc[k] = 0.f;

  int e = start + sub;
  for (; e + 6 < end; e += 8) {          // edges e, e+2, e+4, e+6 in flight
    int j0 = __builtin_amdgcn_readfirstlane(p.src[e]);
    int j1 = __builtin_amdgcn_readfirstlane(p.src[e + 2]);
    int j2 = __builtin_amdgcn_readfirstlane(p.src[e + 4]);
    int j3 = __builtin_amdgcn_readfirstlane(p.src[e + 6]);
    float r0 = hpre[(size_t)j0 * WIDTH + lane];
    float r1 = hpre[(size_t)j1 * WIDTH + lane];
    float r2 = hpre[(size_t)j2 * WIDTH + lane];
    float r3 = hpre[(size_t)j3 * WIDTH + lane];
    const float4* a0 = (const float4*)(p.wbuf + (size_t)e * KDIM);
    const float4* a1 = (const float4*)(p.wbuf + (size_t)(e + 2) * KDIM);
    const float4* a2 = (const float4*)(p.wbuf + (size_t)(e + 4) * KDIM);
    const float4* a3 = (const float4*)(p.wbuf + (size_t)(e + 6) * KDIM);
    float4 w00 = a0[0], w01 = a0[1], w02 = a0[2], w03 = a0[3];
    float4 w10 = a1[0], w11 = a1[1], w12 = a1[2], w13 = a1[3];
    float4 w20 = a2[0], w21 = a2[1], w22 = a2[2], w23 = a2[3];
    float4 w30 = a3[0], w31 = a3[1], w32 = a3[2], w33 = a3[3];
    float hj0 = lrelu(r0 * scH + shH, SLOPE);
    float hj1 = lrelu(r1 * scH + shH, SLOPE);
    float hj2 = lrelu(r2 * scH + shH, SLOPE);
    float hj3 = lrelu(r3 * scH + shH, SLOPE);
    acc[0] += w00.x * hj0; acc[1] += w00.y * hj0; acc[2] += w00.z * hj0; acc[3] += w00.w * hj0;
    acc[4] += w01.x * hj0; acc[5] += w01.y * hj0; acc[6] += w01.z * hj0; acc[7] += w01.w * hj0;
    acc[8] += w02.x * hj0; acc[9] += w02.y * hj0; acc[10] += w02.z * hj0; acc[11] += w02.w * hj0;
    acc[12] += w03.x * hj0; acc[13] += w03.y * hj0; acc[14] += w03.z * hj0; acc[15] += w03.w * hj0;
    acc[0] += w10.x * hj1; acc[1] += w10.y * hj1; acc[2] += w10.z * hj1; acc[3] += w10.w * hj1;
    acc[4] += w11.x * hj1; acc[5] += w11.y * hj1; acc[6] += w11.z * hj1; acc[7] += w11.w * hj1;
    acc[8] += w12.x * hj1; acc[9] += w12.y * hj1; acc[10] += w12.z * hj1; acc[11] += w12.w * hj1;
    acc[12] += w13.x * hj1; acc[13] += w13.y * hj1; acc[14] += w13.z * hj1; acc[15] += w13.w * hj1;
    acc[0] += w20.x * hj2; acc[1] += w20.y * hj2; acc[2] += w20.z * hj2; acc[3] += w20.w * hj2;
    acc[4] += w21.x * hj2; acc[5] += w21.y * hj2; acc[6] += w21.z * hj2; acc[7] += w21.w * hj2;
    acc[8] += w22.x * hj2; acc[9] += w22.y * hj2; acc[10] += w22.z * hj2; acc[11] += w22.w * hj2;
    acc[12] += w23.x * hj2; acc[13] += w23.y * hj2; acc[14] += w23.z * hj2; acc[15] += w23.w * hj2;
    acc[0] += w30.x * hj3; acc[1] += w30.y * hj3; acc[2] += w30.z * hj3; acc[3] += w30.w * hj3;
    acc[4] += w31.x * hj3; acc[5] += w31.y * hj3; acc[6] += w31.z * hj3; acc[7] += w31.w * hj3;
    acc[8] += w32.x * hj3; acc[9] += w32.y * hj3; acc[10] += w32.z * hj3; acc[11] += w32.w * hj3;
    acc[12] += w33.x * hj3; acc[13] += w33.y * hj3; acc[14] += w33.z * hj3; acc[15] += w33.w * hj3;
  }
  for (; e < end; e += 2) {
    int j = __builtin_amdgcn_readfirstlane(p.src[e]);
    float hr = hpre[(size_t)j * WIDTH + lane];
    const float4* w4 = (const float4*)(p.wbuf + (size_t)e * KDIM);
    float4 w0 = w4[0], w1 = w4[1], w2 = w4[2], w3 = w4[3];
    float hj = lrelu(hr * scH + shH, SLOPE);
    acc[0] += w0.x * hj; acc[1] += w0.y * hj; acc[2] += w0.z * hj; acc[3] += w0.w * hj;
    acc[4] += w1.x * hj; acc[5] += w1.y * hj; acc[6] += w1.z * hj; acc[7] += w1.w * hj;
    acc[8] += w2.x * hj; acc[9] += w2.y * hj; acc[10] += w2.z * hj; acc[11] += w2.w * hj;
    acc[12] += w3.x * hj; acc[13] += w3.y * hj; acc[14] += w3.z * hj; acc[15] += w3.w * hj;
  }

#pragma unroll
  for (int k = 0; k < KDIM; k++) lds[wv][k * ALD + lane] = acc[k];
  __syncthreads();

  // combine wave pairs: strip0 += strip1 (node A), strip2 += strip3 (node B)
  for (int i = t; i < KDIM * ALD; i += 256) {
    lds[0][i] += lds[1][i];
    lds[2][i] += lds[3][i];
  }
  __syncthreads();

  // epilogue: each Wf element loaded once, FMA'd into both nodes
  int O = p.O;
  int o = t & (O - 1);
  int q = t / O;
  int kpg = O >> 4;
  float pA = 0.f, pB = 0.f;
  for (int kk = 0; kk < kpg; kk++) {
    int k = q * kpg + kk;
    const float* arA = lds[0] + k * ALD;
    const float* arB = lds[2] + k * ALD;
    const float* wf = p.Wf + (size_t)(k * WIDTH) * O + o;
    for (int c = 0; c < WIDTH; c += 4) {
      float w0 = wf[(size_t)(c + 0) * O];
      float w1 = wf[(size_t)(c + 1) * O];
      float w2 = wf[(size_t)(c + 2) * O];
      float w3 = wf[(size_t)(c + 3) * O];
      float4 a = *(const float4*)(arA + c);
      float4 bb = *(const float4*)(arB + c);
      pA += a.x * w0 + a.y * w1 + a.z * w2 + a.w * w3;
      pB += bb.x * w0 + bb.y * w1 + bb.z * w2 + bb.w * w3;
    }
  }
  for (int m = O; m < 64; m <<= 1) {
    pA += __shfl_xor(pA, m, 64);
    pB += __shfl_xor(pB, m, 64);
  }
  if (lane < O) { pw[wv][0][lane] = pA; pw[wv][1][lane] = pB; }
  __syncthreads();
  if (t < 2 * O) {
    int r = t / O, o2 = t % O;
    cat[(size_t)(nA + r) * WIDTH + p.coloff + o2] =
        pw[0][r][o2] + pw[1][r][o2] + pw[2][r][o2] + pw[3][r][o2];
  }
}

// ============ final: out = lrelu(bn(cat))@outW + ident; 8 nodes/block =======
__global__ __launch_bounds__(256) void final_kernel(
    const float* __restrict__ cat,
    const float* __restrict__ sC, const float* __restrict__ hC,
    const float* __restrict__ outW,
    const float* __restrict__ identity, float* __restrict__ out)
{
  int t = threadIdx.x;
  int n0 = blockIdx.x * 8;
  __shared__ float cn8[8 * WIDTH];
#pragma unroll
  for (int s = 0; s < 2; s++) {
    int ii = s * 256 + t;
    int r = ii >> 6, k = ii & 63;
    cn8[ii] = lrelu(cat[(size_t)(n0 + r) * WIDTH + k] * sC[k] + hC[k], SLOPE);
  }
  __syncthreads();
  float acc[8];
#pragma unroll
  for (int r = 0; r < 8; r++) acc[r] = identity[(size_t)(n0 + r) * COUT + t];
  for (int k = 0; k < WIDTH; k += 4) {
    float w0 = outW[(size_t)(k + 0) * COUT + t];
    float w1 = outW[(size_t)(k + 1) * COUT + t];
    float w2 = outW[(size_t)(k + 2) * COUT + t];
    float w3 = outW[(size_t)(k + 3) * COUT + t];
#pragma unroll
    for (int r = 0; r < 8; r++) {
      float4u a = *(const float4u*)(cn8 + r * WIDTH + k);
      acc[r] += a.x * w0 + a.y * w1 + a.z * w2 + a.w * w3;
    }
  }
#pragma unroll
  for (int r = 0; r < 8; r++) out[(size_t)(n0 + r) * COUT + t] = acc[r];
}

extern "C" void kernel_launch(void* const* d_in, const int* in_sizes, int n_in,
                              void* d_out, int out_size, void* d_ws, size_t ws_size,
                              hipStream_t stream) {
  const float* x    = (const float*)d_in[0];
  const float* pos  = (const float*)d_in[1];
  const float* ori  = (const float*)d_in[2];
  const int* seq  = (const int*)d_in[3];
  const int* src1 = (const int*)d_in[5];  const int* dst1 = (const int*)d_in[6];
  const int* src2 = (const int*)d_in[7];  const int* dst2 = (const int*)d_in[8];
  const int* src3 = (const int*)d_in[9];  const int* dst3 = (const int*)d_in[10];
  const float* id_g  = (const float*)d_in[11]; const float* id_b  = (const float*)d_in[12];
  const float* id_W  = (const float*)d_in[13];
  const float* in_g  = (const float*)d_in[14]; const float* in_b  = (const float*)d_in[15];
  const float* in_W  = (const float*)d_in[16];
  const float* mid_g = (const float*)d_in[17]; const float* mid_b = (const float*)d_in[18];
  const float* Ws1   = (const float*)d_in[19]; const float* bs1   = (const float*)d_in[20];
  const float* W1    = (const float*)d_in[21];
  const float* Ws2   = (const float*)d_in[22]; const float* bs2   = (const float*)d_in[23];
  const float* W2    = (const float*)d_in[24];
  const float* Ws3   = (const float*)d_in[25]; const float* bs3   = (const float*)d_in[26];
  const float* W3    = (const float*)d_in[27];
  const float* out_g = (const float*)d_in[28]; const float* out_b = (const float*)d_in[29];
  const float* out_W = (const float*)d_in[30];

  const int E1 = in_sizes[5], E2 = in_sizes[7], E3 = in_sizes[9];

  float* wsp = (float*)d_ws;
  size_t off = 0;
  auto alloc = [&](size_t n) { float* p = wsp + off; off += (n + 63) & ~(size_t)63; return p; };
  float* sA   = alloc(CIN);   float* hA = alloc(CIN);
  float* sB   = alloc(CIN);   float* hB = alloc(CIN);
  float* sH   = alloc(WIDTH); float* hH = alloc(WIDTH);
  float* sC   = alloc(WIDTH); float* hC = alloc(WIDTH);
  float* ident = alloc((size_t)N_NODES * COUT);
  float* hpre  = alloc((size_t)N_NODES * WIDTH);
  float* catb  = alloc((size_t)N_NODES * WIDTH);
  int*   rowp  = (int*)alloc(3 * (N_NODES + 1));
  float* w1    = alloc((size_t)E1 * KDIM);
  float* w2    = alloc((size_t)E2 * KDIM);
  float* w3    = alloc((size_t)E3 * KDIM);
  (void)ws_size; (void)n_in; (void)out_size;

  int nb1 = (E1 + 255) / 256, nb2 = (E2 + 255) / 256, nb3 = (E3 + 255) / 256;

  EdgeP e0{src1, dst1, Ws1, bs1, w1, E1, 1.0f / 2.70f, 2};
  EdgeP e1{src2, dst2, Ws2, bs2, w2, E2, 1.0f / 1.80f, 3};
  EdgeP e2{src3, dst3, Ws3, bs3, w3, E3, 1.0f / 1.35f, 5};

  // 1. prep: x-stats(+affines) | rowptr | edge gate weights
  prep_kernel<<<NB_STATSX + NB_ROWPTR + nb1 + nb2 + nb3, 256, 0, stream>>>(
      x, id_g, id_b, in_g, in_b, sA, hA, sB, hB, rowp,
      e0, e1, e2, pos, ori, seq, nb1, nb2);
  // 2. both input GEMMs with fused BN+lrelu
  gemm2_kernel<<<1024, 256, 0, stream>>>(x, sA, hA, sB, hB, id_W, in_W, ident, hpre);
  // 3. mid-BN stats -> affine
  stats_affine_kernel<<<WIDTH / 4, 256, 0, stream>>>(hpre, WIDTH, mid_g, mid_b, sH, hH);
  // 4. fused aggregation + branch GEMMs (2 nodes/block, Wf shared)
  AggP a0{src1, w1, W1, 32, 0};
  AggP a1{src2, w2, W2, 16, 32};
  AggP a2{src3, w3, W3, 16, 48};
  agg3_kernel<<<dim3(N_NODES / 2, 3), 256, 0, stream>>>(a0, a1, a2, rowp, hpre, sH, hH, catb);
  // 5. out-BN stats -> affine
  stats_affine_kernel<<<WIDTH / 4, 256, 0, stream>>>(catb, WIDTH, out_g, out_b, sC, hC);
  // 6. final GEMM + residual
  final_kernel<<<N_NODES / 8, 256, 0, stream>>>(catb, sC, hC, out_W, ident, (float*)d_out);
}

// Round 12
// 213.356 us; speedup vs baseline: 2.4825x; 1.0378x over previous
//
#include <hip/hip_runtime.h>

#define N_NODES 4096
#define CIN     128
#define COUT    256
#define WIDTH   64
#define KDIM    16
#define SLOPE   0.1f
#define WSLOPE  0.2f
#define BN_EPS  1e-5f

typedef float float4u __attribute__((ext_vector_type(4), aligned(4)));

__device__ __forceinline__ float lrelu(float x, float s) { return x > 0.f ? x : s * x; }

// ======================= prep: stats_x + rowptr + edge_w =====================
struct EdgeP {
  const int* src; const int* dst;
  const float* Ws; const float* bs;
  float* wbuf; int E; float inv_r; int hl;
};

#define WS_LD 113
#define BS_LD 17
#define NB_STATSX 32
#define NB_ROWPTR 49

__global__ __launch_bounds__(256) void prep_kernel(
    const float* __restrict__ x,
    const float* __restrict__ id_g, const float* __restrict__ id_b,
    const float* __restrict__ in_g, const float* __restrict__ in_b,
    float* __restrict__ sA, float* __restrict__ hA,
    float* __restrict__ sB, float* __restrict__ hB,
    int* __restrict__ rowp,
    EdgeP e0, EdgeP e1, EdgeP e2,
    const float* __restrict__ pos, const float* __restrict__ ori,
    const int* __restrict__ seq,
    int nb1, int nb2)
{
  int bx = blockIdx.x, t = threadIdx.x;

  if (bx < NB_STATSX) {
    int cg = bx;
    int lane = t & 63, wv = t >> 6;
    float s[4] = {0.f, 0.f, 0.f, 0.f}, q[4] = {0.f, 0.f, 0.f, 0.f};
    for (int r = t; r < N_NODES; r += 256) {
      float4u a = *(const float4u*)(x + (size_t)r * CIN + cg * 4);
      float v[4] = {a.x, a.y, a.z, a.w};
#pragma unroll
      for (int i = 0; i < 4; i++) { s[i] += v[i]; q[i] += v[i] * v[i]; }
    }
#pragma unroll
    for (int m = 1; m < 64; m <<= 1) {
#pragma unroll
      for (int i = 0; i < 4; i++) { s[i] += __shfl_xor(s[i], m, 64); q[i] += __shfl_xor(q[i], m, 64); }
    }
    __shared__ float rs[4][4], rq[4][4];
    if (lane == 0) {
#pragma unroll
      for (int i = 0; i < 4; i++) { rs[wv][i] = s[i]; rq[wv][i] = q[i]; }
    }
    __syncthreads();
    if (t < 4) {
      float S = rs[0][t] + rs[1][t] + rs[2][t] + rs[3][t];
      float Q = rq[0][t] + rq[1][t] + rq[2][t] + rq[3][t];
      float m = S / N_NODES;
      float v = Q / N_NODES - m * m;
      float rsv = rsqrtf(v + BN_EPS);
      int c = cg * 4 + t;
      float sa = id_g[c] * rsv;
      float sb = in_g[c] * rsv;
      sA[c] = sa; hA[c] = id_b[c] - m * sa;
      sB[c] = sb; hB[c] = in_b[c] - m * sb;
    }
    return;
  }

  if (bx < NB_STATSX + NB_ROWPTR) {
    int idx = (bx - NB_STATSX) * 256 + t;
    if (idx >= 3 * (N_NODES + 1)) return;
    int b = idx / (N_NODES + 1);
    int n = idx % (N_NODES + 1);
    const int* d = (b == 0) ? e0.dst : (b == 1) ? e1.dst : e2.dst;
    int E = (b == 0) ? e0.E : (b == 1) ? e1.E : e2.E;
    int lo = 0, hi = E;
    if (n >= N_NODES) lo = E;
    else {
      while (lo < hi) { int mid = (lo + hi) >> 1; if (d[mid] < n) lo = mid + 1; else hi = mid; }
    }
    rowp[(size_t)b * (N_NODES + 1) + n] = lo;
    return;
  }

  // ---- per-edge gate weights ----
  int eb = bx - (NB_STATSX + NB_ROWPTR);
  EdgeP p;
  int base;
  if (eb < nb1)            { p = e0; base = eb; }
  else if (eb < nb1 + nb2) { p = e1; base = eb - nb1; }
  else                     { p = e2; base = eb - nb1 - nb2; }

  __shared__ float wsl[11 * WS_LD];
  __shared__ float bsl[11 * BS_LD];
  int L = 2 * p.hl + 1;
  for (int i = t; i < L * 112; i += 256) {
    int bin = i / 112, r = i - bin * 112;
    wsl[bin * WS_LD + r] = p.Ws[(size_t)bin * 112 + r];
  }
  for (int i = t; i < L * 16; i += 256) {
    int bin = i >> 4, r = i & 15;
    bsl[bin * BS_LD + r] = p.bs[(size_t)bin * 16 + r];
  }
  __syncthreads();

  int e = base * 256 + t;
  if (e >= p.E) return;
  int j = p.src[e], i = p.dst[e];
  float px = pos[j * 3 + 0] - pos[i * 3 + 0];
  float py = pos[j * 3 + 1] - pos[i * 3 + 1];
  float pz = pos[j * 3 + 2] - pos[i * 3 + 2];
  float fi[9], fj[9];
  {
    float4u a0 = *(const float4u*)(ori + (size_t)i * 9);
    float4u a1 = *(const float4u*)(ori + (size_t)i * 9 + 4);
    fi[0] = a0.x; fi[1] = a0.y; fi[2] = a0.z; fi[3] = a0.w;
    fi[4] = a1.x; fi[5] = a1.y; fi[6] = a1.z; fi[7] = a1.w;
    fi[8] = ori[(size_t)i * 9 + 8];
    float4u b0 = *(const float4u*)(ori + (size_t)j * 9);
    float4u b1 = *(const float4u*)(ori + (size_t)j * 9 + 4);
    fj[0] = b0.x; fj[1] = b0.y; fj[2] = b0.z; fj[3] = b0.w;
    fj[4] = b1.x; fj[5] = b1.y; fj[6] = b1.z; fj[7] = b1.w;
    fj[8] = ori[(size_t)j * 9 + 8];
  }
  float dist = sqrtf(px * px + py * py + pz * pz);
  float inv = 1.0f / (dist + 1e-9f);
  float dx = px * inv, dy = py * inv, dz = pz * inv;
  float feat[7];
  feat[0] = dist * p.inv_r;
  feat[1] = fi[0] * dx + fi[1] * dy + fi[2] * dz;
  feat[2] = fi[3] * dx + fi[4] * dy + fi[5] * dz;
  feat[3] = fi[6] * dx + fi[7] * dy + fi[8] * dz;
  feat[4] = fi[0] * fj[0] + fi[1] * fj[1] + fi[2] * fj[2];
  feat[5] = fi[3] * fj[3] + fi[4] * fj[4] + fi[5] * fj[5];
  feat[6] = fi[6] * fj[6] + fi[7] * fj[7] + fi[8] * fj[8];
  int d = seq[j] - seq[i];
  d = d < -p.hl ? -p.hl : (d > p.hl ? p.hl : d);
  int bin = d + p.hl;
  const float* Wp = wsl + bin * WS_LD;
  const float* bp = bsl + bin * BS_LD;
  float w16[KDIM];
#pragma unroll
  for (int k = 0; k < KDIM; k++) {
    float a = bp[k];
#pragma unroll
    for (int c = 0; c < 7; c++) a += feat[c] * Wp[c * KDIM + k];
    w16[k] = lrelu(a, WSLOPE);
  }
  float4* wb = (float4*)(p.wbuf + (size_t)e * KDIM);
#pragma unroll
  for (int k = 0; k < 4; k++)
    wb[k] = make_float4(w16[4 * k], w16[4 * k + 1], w16[4 * k + 2], w16[4 * k + 3]);
}

// =========== gemm2: ident = act_id(x)@id_W | hpre = act_in(x)@in_W ==========
// 4 rows/block for TLP: blocks [0,1024) cout path, [1024,2048) w64 path.
__global__ __launch_bounds__(256) void gemm2_kernel(
    const float* __restrict__ x,
    const float* __restrict__ sA, const float* __restrict__ hA,
    const float* __restrict__ sB, const float* __restrict__ hB,
    const float* __restrict__ idW, const float* __restrict__ inW,
    float* __restrict__ ident, float* __restrict__ hpre)
{
  int bx = blockIdx.x, t = threadIdx.x;
  __shared__ float at[4 * CIN];   // 2 KB, bn+lrelu applied
  bool coutp = bx < 1024;
  int n0 = (coutp ? bx : bx - 1024) * 4;
  if (t < 128) {
    int r = t >> 5, c4 = (t & 31) * 4;
    const float* S = coutp ? sA : sB;
    const float* H = coutp ? hA : hB;
    float4u xv = *(const float4u*)(x + (size_t)(n0 + r) * CIN + c4);
    float4u sv = *(const float4u*)(S + c4);
    float4u hv = *(const float4u*)(H + c4);
    float4u o;
    o.x = lrelu(xv.x * sv.x + hv.x, SLOPE);
    o.y = lrelu(xv.y * sv.y + hv.y, SLOPE);
    o.z = lrelu(xv.z * sv.z + hv.z, SLOPE);
    o.w = lrelu(xv.w * sv.w + hv.w, SLOPE);
    *(float4u*)(at + r * CIN + c4) = o;
  }
  __syncthreads();
  if (coutp) {
    float acc[4] = {0.f, 0.f, 0.f, 0.f};
    for (int k = 0; k < CIN; k += 4) {
      float w0 = idW[(size_t)(k + 0) * COUT + t];
      float w1 = idW[(size_t)(k + 1) * COUT + t];
      float w2 = idW[(size_t)(k + 2) * COUT + t];
      float w3 = idW[(size_t)(k + 3) * COUT + t];
#pragma unroll
      for (int r4 = 0; r4 < 4; r4++) {
        float4u a = *(const float4u*)(at + r4 * CIN + k);
        acc[r4] += a.x * w0 + a.y * w1 + a.z * w2 + a.w * w3;
      }
    }
#pragma unroll
    for (int r4 = 0; r4 < 4; r4++) ident[(size_t)(n0 + r4) * COUT + t] = acc[r4];
  } else {
    int j = t & 63, g = t >> 6;   // wave g -> row g
    float a0 = 0.f;
    for (int k = 0; k < CIN; k += 4) {
      float w0 = inW[(size_t)(k + 0) * WIDTH + j];
      float w1 = inW[(size_t)(k + 1) * WIDTH + j];
      float w2 = inW[(size_t)(k + 2) * WIDTH + j];
      float w3 = inW[(size_t)(k + 3) * WIDTH + j];
      float4u u = *(const float4u*)(at + g * CIN + k);
      a0 += u.x * w0 + u.y * w1 + u.z * w2 + u.w * w3;
    }
    hpre[(size_t)(n0 + g) * WIDTH + j] = a0;
  }
}

// ====== stats_affine: col stats of X[4096,C] -> s = g*rsqrt(v+eps), h = b-m*s
__global__ __launch_bounds__(256) void stats_affine_kernel(
    const float* __restrict__ X, int C,
    const float* __restrict__ g, const float* __restrict__ b,
    float* __restrict__ s_out, float* __restrict__ h_out)
{
  int cg = blockIdx.x;
  int t = threadIdx.x, lane = t & 63, wv = t >> 6;
  float s[4] = {0.f, 0.f, 0.f, 0.f}, q[4] = {0.f, 0.f, 0.f, 0.f};
  for (int r = t; r < N_NODES; r += 256) {
    float4u a = *(const float4u*)(X + (size_t)r * C + cg * 4);
    float v[4] = {a.x, a.y, a.z, a.w};
#pragma unroll
    for (int i = 0; i < 4; i++) { s[i] += v[i]; q[i] += v[i] * v[i]; }
  }
#pragma unroll
  for (int m = 1; m < 64; m <<= 1) {
#pragma unroll
    for (int i = 0; i < 4; i++) { s[i] += __shfl_xor(s[i], m, 64); q[i] += __shfl_xor(q[i], m, 64); }
  }
  __shared__ float rs[4][4], rq[4][4];
  if (lane == 0) {
#pragma unroll
    for (int i = 0; i < 4; i++) { rs[wv][i] = s[i]; rq[wv][i] = q[i]; }
  }
  __syncthreads();
  if (t < 4) {
    float S = rs[0][t] + rs[1][t] + rs[2][t] + rs[3][t];
    float Q = rq[0][t] + rq[1][t] + rq[2][t] + rq[3][t];
    float m = S / N_NODES;
    float v = Q / N_NODES - m * m;
    int c = cg * 4 + t;
    float sv = g[c] * rsqrtf(v + BN_EPS);
    s_out[c] = sv;
    h_out[c] = b[c] - m * sv;
  }
}

// ====== agg3: 4 nodes/block, 512 threads (8 waves); wave-pairs per node; ====
// ====== epilogue shares each Wf load across all 4 nodes (L2 traffic /4) =====
struct AggP {
  const int* src; const float* wbuf; const float* Wf;
  int O; int coloff;
};

#define ALD 68   // padded k-row stride

__global__ __launch_bounds__(512, 4) void agg3_kernel(
    AggP p0, AggP p1, AggP p2, const int* __restrict__ rowp,
    const float* __restrict__ hpre,
    const float* __restrict__ sH, const float* __restrict__ hH,
    float* __restrict__ cat)
{
  int b = blockIdx.y;
  AggP p = (b == 0) ? p0 : (b == 1) ? p1 : p2;
  int nA = blockIdx.x * 4, t = threadIdx.x, lane = t & 63, wv = t >> 6;  // wv 0..7

  __shared__ float lds[8][KDIM * ALD];   // 34.8 KB
  __shared__ float pw[8][4][32];         // wave, node, col (4 KB)
  __shared__ float sHl[WIDTH], hHl[WIDTH];
  if (t < WIDTH) { sHl[t] = sH[t]; hHl[t] = hH[t]; }
  __syncthreads();
  float scH = sHl[lane], shH = hHl[lane];

  // wave pair (2r, 2r+1) -> node nA+r; pair splits edges stride 2
  int n = nA + (wv >> 1);
  int sub = wv & 1;
  const int* rp = rowp + (size_t)b * (N_NODES + 1);
  int start = rp[n], end = rp[n + 1];

  float acc[KDIM];
#pragma unroll
  for (int k = 0; k < KDIM; k++) acc[k] = 0.f;

  int e = start + sub;
  for (; e + 6 < end; e += 8) {          // edges e, e+2, e+4, e+6 in flight
    int j0 = __builtin_amdgcn_readfirstlane(p.src[e]);
    int j1 = __builtin_amdgcn_readfirstlane(p.src[e + 2]);
    int j2 = __builtin_amdgcn_readfirstlane(p.src[e + 4]);
    int j3 = __builtin_amdgcn_readfirstlane(p.src[e + 6]);
    float r0 = hpre[(size_t)j0 * WIDTH + lane];
    float r1 = hpre[(size_t)j1 * WIDTH + lane];
    float r2 = hpre[(size_t)j2 * WIDTH + lane];
    float r3 = hpre[(size_t)j3 * WIDTH + lane];
    const float4* a0 = (const float4*)(p.wbuf + (size_t)e * KDIM);
    const float4* a1 = (const float4*)(p.wbuf + (size_t)(e + 2) * KDIM);
    const float4* a2 = (const float4*)(p.wbuf + (size_t)(e + 4) * KDIM);
    const float4* a3 = (const float4*)(p.wbuf + (size_t)(e + 6) * KDIM);
    float4 w00 = a0[0], w01 = a0[1], w02 = a0[2], w03 = a0[3];
    float4 w10 = a1[0], w11 = a1[1], w12 = a1[2], w13 = a1[3];
    float4 w20 = a2[0], w21 = a2[1], w22 = a2[2], w23 = a2[3];
    float4 w30 = a3[0], w31 = a3[1], w32 = a3[2], w33 = a3[3];
    float hj0 = lrelu(r0 * scH + shH, SLOPE);
    float hj1 = lrelu(r1 * scH + shH, SLOPE);
    float hj2 = lrelu(r2 * scH + shH, SLOPE);
    float hj3 = lrelu(r3 * scH + shH, SLOPE);
    acc[0] += w00.x * hj0; acc[1] += w00.y * hj0; acc[2] += w00.z * hj0; acc[3] += w00.w * hj0;
    acc[4] += w01.x * hj0; acc[5] += w01.y * hj0; acc[6] += w01.z * hj0; acc[7] += w01.w * hj0;
    acc[8] += w02.x * hj0; acc[9] += w02.y * hj0; acc[10] += w02.z * hj0; acc[11] += w02.w * hj0;
    acc[12] += w03.x * hj0; acc[13] += w03.y * hj0; acc[14] += w03.z * hj0; acc[15] += w03.w * hj0;
    acc[0] += w10.x * hj1; acc[1] += w10.y * hj1; acc[2] += w10.z * hj1; acc[3] += w10.w * hj1;
    acc[4] += w11.x * hj1; acc[5] += w11.y * hj1; acc[6] += w11.z * hj1; acc[7] += w11.w * hj1;
    acc[8] += w12.x * hj1; acc[9] += w12.y * hj1; acc[10] += w12.z * hj1; acc[11] += w12.w * hj1;
    acc[12] += w13.x * hj1; acc[13] += w13.y * hj1; acc[14] += w13.z * hj1; acc[15] += w13.w * hj1;
    acc[0] += w20.x * hj2; acc[1] += w20.y * hj2; acc[2] += w20.z * hj2; acc[3] += w20.w * hj2;
    acc[4] += w21.x * hj2; acc[5] += w21.y * hj2; acc[6] += w21.z * hj2; acc[7] += w21.w * hj2;
    acc[8] += w22.x * hj2; acc[9] += w22.y * hj2; acc[10] += w22.z * hj2; acc[11] += w22.w * hj2;
    acc[12] += w23.x * hj2; acc[13] += w23.y * hj2; acc[14] += w23.z * hj2; acc[15] += w23.w * hj2;
    acc[0] += w30.x * hj3; acc[1] += w30.y * hj3; acc[2] += w30.z * hj3; acc[3] += w30.w * hj3;
    acc[4] += w31.x * hj3; acc[5] += w31.y * hj3; acc[6] += w31.z * hj3; acc[7] += w31.w * hj3;
    acc[8] += w32.x * hj3; acc[9] += w32.y * hj3; acc[10] += w32.z * hj3; acc[11] += w32.w * hj3;
    acc[12] += w33.x * hj3; acc[13] += w33.y * hj3; acc[14] += w33.z * hj3; acc[15] += w33.w * hj3;
  }
  for (; e < end; e += 2) {
    int j = __builtin_amdgcn_readfirstlane(p.src[e]);
    float hr = hpre[(size_t)j * WIDTH + lane];
    const float4* w4 = (const float4*)(p.wbuf + (size_t)e * KDIM);
    float4 w0 = w4[0], w1 = w4[1], w2 = w4[2], w3 = w4[3];
    float hj = lrelu(hr * scH + shH, SLOPE);
    acc[0] += w0.x * hj; acc[1] += w0.y * hj; acc[2] += w0.z * hj; acc[3] += w0.w * hj;
    acc[4] += w1.x * hj; acc[5] += w1.y * hj; acc[6] += w1.z * hj; acc[7] += w1.w * hj;
    acc[8] += w2.x * hj; acc[9] += w2.y * hj; acc[10] += w2.z * hj; acc[11] += w2.w * hj;
    acc[12] += w3.x * hj; acc[13] += w3.y * hj; acc[14] += w3.z * hj; acc[15] += w3.w * hj;
  }

#pragma unroll
  for (int k = 0; k < KDIM; k++) lds[wv][k * ALD + lane] = acc[k];
  __syncthreads();

  // combine wave pairs: strip 2r += strip 2r+1 (node r in strip 2r)
  for (int i = t; i < KDIM * ALD; i += 512) {
    lds[0][i] += lds[1][i];
    lds[2][i] += lds[3][i];
    lds[4][i] += lds[5][i];
    lds[6][i] += lds[7][i];
  }
  __syncthreads();

  // epilogue: each Wf element loaded once, FMA'd into all 4 nodes
  int O = p.O;
  int o = t & (O - 1);
  int q = t / O;                          // O=32: 16 groups (k=q); O=16: 32
  float pA = 0.f, pB = 0.f, pC = 0.f, pD = 0.f;
  int k, c0, clen;
  if (O == 32) { k = q; c0 = 0; clen = WIDTH; }          // one k per group
  else { k = q >> 1; c0 = (q & 1) * 32; clen = 32; }     // k + c-half
  {
    const float* arA = lds[0] + k * ALD + c0;
    const float* arB = lds[2] + k * ALD + c0;
    const float* arC = lds[4] + k * ALD + c0;
    const float* arD = lds[6] + k * ALD + c0;
    const float* wf = p.Wf + (size_t)(k * WIDTH + c0) * O + o;
    for (int c = 0; c < clen; c += 4) {
      float w0 = wf[(size_t)(c + 0) * O];
      float w1 = wf[(size_t)(c + 1) * O];
      float w2 = wf[(size_t)(c + 2) * O];
      float w3 = wf[(size_t)(c + 3) * O];
      float4 aA = *(const float4*)(arA + c);
      float4 aB = *(const float4*)(arB + c);
      float4 aC = *(const float4*)(arC + c);
      float4 aD = *(const float4*)(arD + c);
      pA += aA.x * w0 + aA.y * w1 + aA.z * w2 + aA.w * w3;
      pB += aB.x * w0 + aB.y * w1 + aB.z * w2 + aB.w * w3;
      pC += aC.x * w0 + aC.y * w1 + aC.z * w2 + aC.w * w3;
      pD += aD.x * w0 + aD.y * w1 + aD.z * w2 + aD.w * w3;
    }
  }
  for (int m = O; m < 64; m <<= 1) {
    pA += __shfl_xor(pA, m, 64);
    pB += __shfl_xor(pB, m, 64);
    pC += __shfl_xor(pC, m, 64);
    pD += __shfl_xor(pD, m, 64);
  }
  if (lane < O) {
    pw[wv][0][lane] = pA; pw[wv][1][lane] = pB;
    pw[wv][2][lane] = pC; pw[wv][3][lane] = pD;
  }
  __syncthreads();
  if (t < 4 * O) {
    int r = t / O, o2 = t % O;
    float v = 0.f;
#pragma unroll
    for (int w = 0; w < 8; w++) v += pw[w][r][o2];
    cat[(size_t)(nA + r) * WIDTH + p.coloff + o2] = v;
  }
}

// ============ final: out = lrelu(bn(cat))@outW + ident; 4 nodes/block =======
__global__ __launch_bounds__(256) void final_kernel(
    const float* __restrict__ cat,
    const float* __restrict__ sC, const float* __restrict__ hC,
    const float* __restrict__ outW,
    const float* __restrict__ identity, float* __restrict__ out)
{
  int t = threadIdx.x;
  int n0 = blockIdx.x * 4;
  __shared__ float cn4[4 * WIDTH];
  {
    int r = t >> 6, k = t & 63;   // 256 threads = 4x64 exactly
    cn4[t] = lrelu(cat[(size_t)(n0 + r) * WIDTH + k] * sC[k] + hC[k], SLOPE);
  }
  __syncthreads();
  float acc[4];
#pragma unroll
  for (int r = 0; r < 4; r++) acc[r] = identity[(size_t)(n0 + r) * COUT + t];
  for (int k = 0; k < WIDTH; k += 4) {
    float w0 = outW[(size_t)(k + 0) * COUT + t];
    float w1 = outW[(size_t)(k + 1) * COUT + t];
    float w2 = outW[(size_t)(k + 2) * COUT + t];
    float w3 = outW[(size_t)(k + 3) * COUT + t];
#pragma unroll
    for (int r = 0; r < 4; r++) {
      float4u a = *(const float4u*)(cn4 + r * WIDTH + k);
      acc[r] += a.x * w0 + a.y * w1 + a.z * w2 + a.w * w3;
    }
  }
#pragma unroll
  for (int r = 0; r < 4; r++) out[(size_t)(n0 + r) * COUT + t] = acc[r];
}

extern "C" void kernel_launch(void* const* d_in, const int* in_sizes, int n_in,
                              void* d_out, int out_size, void* d_ws, size_t ws_size,
                              hipStream_t stream) {
  const float* x    = (const float*)d_in[0];
  const float* pos  = (const float*)d_in[1];
  const float* ori  = (const float*)d_in[2];
  const int* seq  = (const int*)d_in[3];
  const int* src1 = (const int*)d_in[5];  const int* dst1 = (const int*)d_in[6];
  const int* src2 = (const int*)d_in[7];  const int* dst2 = (const int*)d_in[8];
  const int* src3 = (const int*)d_in[9];  const int* dst3 = (const int*)d_in[10];
  const float* id_g  = (const float*)d_in[11]; const float* id_b  = (const float*)d_in[12];
  const float* id_W  = (const float*)d_in[13];
  const float* in_g  = (const float*)d_in[14]; const float* in_b  = (const float*)d_in[15];
  const float* in_W  = (const float*)d_in[16];
  const float* mid_g = (const float*)d_in[17]; const float* mid_b = (const float*)d_in[18];
  const float* Ws1   = (const float*)d_in[19]; const float* bs1   = (const float*)d_in[20];
  const float* W1    = (const float*)d_in[21];
  const float* Ws2   = (const float*)d_in[22]; const float* bs2   = (const float*)d_in[23];
  const float* W2    = (const float*)d_in[24];
  const float* Ws3   = (const float*)d_in[25]; const float* bs3   = (const float*)d_in[26];
  const float* W3    = (const float*)d_in[27];
  const float* out_g = (const float*)d_in[28]; const float* out_b = (const float*)d_in[29];
  const float* out_W = (const float*)d_in[30];

  const int E1 = in_sizes[5], E2 = in_sizes[7], E3 = in_sizes[9];

  float* wsp = (float*)d_ws;
  size_t off = 0;
  auto alloc = [&](size_t n) { float* p = wsp + off; off += (n + 63) & ~(size_t)63; return p; };
  float* sA   = alloc(CIN);   float* hA = alloc(CIN);
  float* sB   = alloc(CIN);   float* hB = alloc(CIN);
  float* sH   = alloc(WIDTH); float* hH = alloc(WIDTH);
  float* sC   = alloc(WIDTH); float* hC = alloc(WIDTH);
  float* ident = alloc((size_t)N_NODES * COUT);
  float* hpre  = alloc((size_t)N_NODES * WIDTH);
  float* catb  = alloc((size_t)N_NODES * WIDTH);
  int*   rowp  = (int*)alloc(3 * (N_NODES + 1));
  float* w1    = alloc((size_t)E1 * KDIM);
  float* w2    = alloc((size_t)E2 * KDIM);
  float* w3    = alloc((size_t)E3 * KDIM);
  (void)ws_size; (void)n_in; (void)out_size;

  int nb1 = (E1 + 255) / 256, nb2 = (E2 + 255) / 256, nb3 = (E3 + 255) / 256;

  EdgeP e0{src1, dst1, Ws1, bs1, w1, E1, 1.0f / 2.70f, 2};
  EdgeP e1{src2, dst2, Ws2, bs2, w2, E2, 1.0f / 1.80f, 3};
  EdgeP e2{src3, dst3, Ws3, bs3, w3, E3, 1.0f / 1.35f, 5};

  // 1. prep: x-stats(+affines) | rowptr | edge gate weights
  prep_kernel<<<NB_STATSX + NB_ROWPTR + nb1 + nb2 + nb3, 256, 0, stream>>>(
      x, id_g, id_b, in_g, in_b, sA, hA, sB, hB, rowp,
      e0, e1, e2, pos, ori, seq, nb1, nb2);
  // 2. both input GEMMs with fused BN+lrelu (4 rows/block)
  gemm2_kernel<<<2048, 256, 0, stream>>>(x, sA, hA, sB, hB, id_W, in_W, ident, hpre);
  // 3. mid-BN stats -> affine
  stats_affine_kernel<<<WIDTH / 4, 256, 0, stream>>>(hpre, WIDTH, mid_g, mid_b, sH, hH);
  // 4. fused aggregation + branch GEMMs (4 nodes/block, Wf shared x4)
  AggP a0{src1, w1, W1, 32, 0};
  AggP a1{src2, w2, W2, 16, 32};
  AggP a2{src3, w3, W3, 16, 48};
  agg3_kernel<<<dim3(N_NODES / 4, 3), 512, 0, stream>>>(a0, a1, a2, rowp, hpre, sH, hH, catb);
  // 5. out-BN stats -> affine
  stats_affine_kernel<<<WIDTH / 4, 256, 0, stream>>>(catb, WIDTH, out_g, out_b, sC, hC);
  // 6. final GEMM + residual (4 nodes/block)
  final_kernel<<<N_NODES / 4, 256, 0, stream>>>(catb, sC, hC, out_W, ident, (float*)d_out);
}